// Round 2
// baseline (985.485 us; speedup 1.0000x reference)
//
#include <hip/hip_runtime.h>
#include <hip/hip_bf16.h>
#include <math.h>

#define SEQ 2048
#define EMB 256
#define DIN 264   // EMB + HID
#define TAGS 50

__device__ __forceinline__ float fast_sig(float x) { return 1.f / (1.f + __expf(-x)); }
__device__ __forceinline__ float fast_tanh(float x) { float e = __expf(2.f * x); return (e - 1.f) / (e + 1.f); }

// dtype-flexible load: F32 ? float32 : bf16
template<bool F32>
__device__ __forceinline__ float ldf(const void* p, int i) {
    if constexpr (F32) {
        return ((const float*)p)[i];
    } else {
        unsigned int u = ((const unsigned short*)p)[i];
        return __uint_as_float(u << 16);
    }
}

// Kernel 0: probe emb_table's raw 16-bit halves. Genuine bf16 ~N(0,0.05)
// has exponents in ~[113,127]; float32 read as 16-bit halves gives random
// exponents on every low half (~110/256 "bad"). flag: 1 = float32, 0 = bf16.
__global__ void k_probe(const void* __restrict__ emb, int* __restrict__ flag) {
    if (threadIdx.x == 0) {
        const unsigned short* p = (const unsigned short*)emb;
        int bad = 0;
        for (int i = 0; i < 256; ++i) {
            int ex = (p[i] >> 7) & 0xFF;
            if (ex == 0xFF || ex > 130 || (ex != 0 && ex < 100)) bad++;
        }
        *flag = (bad > 20) ? 1 : 0;
    }
}

// ---------------- Kernel 1: parallel pre-activations ----------------
// pre[t*32 + g*8 + w] = emb_t . W_g[w,:256] + b_g[w] + th_g[w]
template<bool F32>
__device__ __forceinline__ void pre_body(
    const int* __restrict__ sentence, const void* __restrict__ emb,
    const void* Wf, const void* bf_, const void* Wi, const void* bi,
    const void* Wu, const void* bu, const void* Wo, const void* bo,
    const void* thf, const void* thi, const void* thu, const void* tho,
    float* __restrict__ pre, float* se)
{
    const int t = blockIdx.x;
    const int tid = threadIdx.x;
    const int row = sentence[t];
    se[tid] = ldf<F32>(emb, row * EMB + tid);
    __syncthreads();
    const int u = tid >> 3;      // 0..31 output unit (g*8+w)
    const int j = tid & 7;       // 8 threads per unit
    const int g = u >> 3, w = u & 7;
    const void* W  = (g == 0) ? Wf  : (g == 1) ? Wi  : (g == 2) ? Wu  : Wo;
    const void* b  = (g == 0) ? bf_ : (g == 1) ? bi  : (g == 2) ? bu  : bo;
    const void* th = (g == 0) ? thf : (g == 1) ? thi : (g == 2) ? thu : tho;
    float s = 0.f;
    #pragma unroll
    for (int m = 0; m < EMB / 8; ++m) {
        int k = j + m * 8;
        s += se[k] * ldf<F32>(W, w * DIN + k);
    }
    s += __shfl_xor(s, 1, 8);
    s += __shfl_xor(s, 2, 8);
    s += __shfl_xor(s, 4, 8);
    if (j == 0) pre[t * 32 + u] = s + ldf<F32>(b, w) + ldf<F32>(th, w);
}

__global__ __launch_bounds__(256) void k_pre(
    const int* __restrict__ flag,
    const int* __restrict__ sentence, const void* __restrict__ emb,
    const void* Wf, const void* bf_, const void* Wi, const void* bi,
    const void* Wu, const void* bu, const void* Wo, const void* bo,
    const void* thf, const void* thi, const void* thu, const void* tho,
    float* __restrict__ pre)
{
    __shared__ float se[EMB];
    if (*flag)
        pre_body<true >(sentence, emb, Wf, bf_, Wi, bi, Wu, bu, Wo, bo, thf, thi, thu, tho, pre, se);
    else
        pre_body<false>(sentence, emb, Wf, bf_, Wi, bi, Wu, bu, Wo, bo, thf, thi, thu, tho, pre, se);
}

// ---------------- Kernel 2: serial recurrence (one wave) ----------------
// Lane = g*8 + w for lanes 0..31 (lanes 32-63 duplicate group structure).
template<bool F32>
__device__ __forceinline__ void seq_body(
    const void* Wf, const void* Wi, const void* Wu, const void* Wo,
    const float* __restrict__ pre, float* __restrict__ hbuf)
{
    const int lane = threadIdx.x;
    const int lane32 = lane & 31;
    const int g = lane32 >> 3;
    const int w = lane & 7;
    const void* W = (g == 0) ? Wf : (g == 1) ? Wi : (g == 2) ? Wu : Wo;
    float Whx[8];
    #pragma unroll
    for (int k = 0; k < 8; ++k) Whx[k] = ldf<F32>(W, w * DIN + EMB + k);
    float hx[8];
    #pragma unroll
    for (int k = 0; k < 8; ++k) hx[k] = 0.f;
    float cx = 0.f;
    const bool ge1 = (w >= 1), ge2 = (w >= 2), ge4 = (w >= 4);
    const int base = lane & ~7;
    float pre_next = pre[lane32];

    for (int t = 0; t < SEQ; ++t) {
        float pv = pre_next;
        if (t + 1 < SEQ) pre_next = pre[(t + 1) * 32 + lane32];  // prefetch
        float phi = pv;
        #pragma unroll
        for (int k = 0; k < 8; ++k) phi += hx[k] * Whx[k];
        float c = __cosf(phi);
        // inclusive product scan over each 8-lane group: T_w = prod_{j=1..w} c_j
        float d = ge1 ? c : 1.0f;
        float tt;
        tt = __shfl_up(d, 1, 8); if (ge1) d *= tt;
        tt = __shfl_up(d, 2, 8); if (ge2) d *= tt;
        tt = __shfl_up(d, 4, 8); if (ge4) d *= tt;
        // out[w>=1] = c0 * T_w ; out[0] = T_7
        float c0 = __shfl(c, base, 64);
        float T7 = __shfl(d, base + 7, 64);
        float outv = (w == 0) ? T7 : c0 * d;
        float act = (g == 2) ? fast_tanh(outv) : fast_sig(outv);
        // gather f,i,g,o for wire = lane (lanes 0..7 meaningful)
        float fv = __shfl(act, w, 64);
        float iv = __shfl(act, w + 8, 64);
        float gv = __shfl(act, w + 16, 64);
        float ov = __shfl(act, w + 24, 64);
        cx = fv * cx + iv * gv;
        float hv = ov * fast_tanh(cx);
        if (lane < 8) hbuf[t * 8 + lane] = hv;
        #pragma unroll
        for (int k = 0; k < 8; ++k)
            hx[k] = __int_as_float(__builtin_amdgcn_readlane(__float_as_int(hv), k));
    }
}

__global__ __launch_bounds__(64) void k_seq(
    const int* __restrict__ flag,
    const void* Wf, const void* Wi, const void* Wu, const void* Wo,
    const float* __restrict__ pre, float* __restrict__ hbuf)
{
    if (*flag) seq_body<true >(Wf, Wi, Wu, Wo, pre, hbuf);
    else       seq_body<false>(Wf, Wi, Wu, Wo, pre, hbuf);
}

// ---------------- Kernel 3: head + log_softmax (one wave / t) ----------------
template<bool F32>
__device__ __forceinline__ void head_body(
    const float* __restrict__ hbuf, const void* Wt, const void* bt,
    void* __restrict__ out)
{
    const int t = blockIdx.x;
    const int l = threadIdx.x;
    float hk[8];
    #pragma unroll
    for (int k = 0; k < 8; ++k) hk[k] = hbuf[t * 8 + k];
    float logit = -INFINITY;
    if (l < TAGS) {
        logit = ldf<F32>(bt, l);
        #pragma unroll
        for (int k = 0; k < 8; ++k) logit += hk[k] * ldf<F32>(Wt, l * 8 + k);
    }
    float m = logit;
    #pragma unroll
    for (int s = 32; s >= 1; s >>= 1) m = fmaxf(m, __shfl_xor(m, s, 64));
    float e = (l < TAGS) ? __expf(logit - m) : 0.f;
    float sum = e;
    #pragma unroll
    for (int s = 32; s >= 1; s >>= 1) sum += __shfl_xor(sum, s, 64);
    if (l < TAGS) {
        float v = logit - m - __logf(sum);
        if constexpr (F32) ((float*)out)[t * TAGS + l] = v;
        else ((unsigned short*)out)[t * TAGS + l] =
                 (unsigned short)(( __float_as_uint(v) + 0x8000u +
                                    ((__float_as_uint(v) >> 16) & 1u)) >> 16);  // RNE bf16
    }
}

__global__ __launch_bounds__(64) void k_head(
    const int* __restrict__ flag,
    const float* __restrict__ hbuf, const void* Wt, const void* bt,
    void* __restrict__ out)
{
    if (*flag) head_body<true >(hbuf, Wt, bt, out);
    else       head_body<false>(hbuf, Wt, bt, out);
}

extern "C" void kernel_launch(void* const* d_in, const int* in_sizes, int n_in,
                              void* d_out, int out_size, void* d_ws, size_t ws_size,
                              hipStream_t stream) {
    (void)in_sizes; (void)n_in; (void)out_size; (void)ws_size;
    const int* sentence = (const int*)d_in[0];
    const void* emb = d_in[1];
    const void* Wf = d_in[2];  const void* bf_ = d_in[3];
    const void* Wi = d_in[4];  const void* bi = d_in[5];
    const void* Wu = d_in[6];  const void* bu = d_in[7];
    const void* Wo = d_in[8];  const void* bo = d_in[9];
    const void* thf = d_in[10]; const void* thi = d_in[11];
    const void* thu = d_in[12]; const void* tho = d_in[13];
    const void* Wt = d_in[14]; const void* bt = d_in[15];

    int* flag   = (int*)d_ws;
    float* pre  = (float*)d_ws + 16;     // 64B offset
    float* hbuf = pre + SEQ * 32;

    k_probe<<<dim3(1), dim3(64), 0, stream>>>(emb, flag);
    k_pre<<<dim3(SEQ), dim3(256), 0, stream>>>(flag, sentence, emb,
        Wf, bf_, Wi, bi, Wu, bu, Wo, bo, thf, thi, thu, tho, pre);
    k_seq<<<dim3(1), dim3(64), 0, stream>>>(flag, Wf, Wi, Wu, Wo, pre, hbuf);
    k_head<<<dim3(SEQ), dim3(64), 0, stream>>>(flag, hbuf, Wt, bt, d_out);
}

// Round 3
// 740.779 us; speedup vs baseline: 1.3303x; 1.3303x over previous
//
#include <hip/hip_runtime.h>
#include <hip/hip_bf16.h>
#include <math.h>

#define SEQ 2048
#define EMB 256
#define DIN 264   // EMB + HID
#define TAGS 50

// dtype-flexible load: F32 ? float32 : bf16
template<bool F32>
__device__ __forceinline__ float ldf(const void* p, int i) {
    if constexpr (F32) {
        return ((const float*)p)[i];
    } else {
        unsigned int u = ((const unsigned short*)p)[i];
        return __uint_as_float(u << 16);
    }
}

// Per-wave dtype probe on raw 16-bit halves of emb. bf16 ~N(0,0.05): exponents
// cluster in ~[113,127] -> ~0 bad. float32 read as halves: low halves are
// mantissa bits -> ~28/64 bad. Returns true if data is float32.
__device__ __forceinline__ bool probe_f32(const void* emb) {
    unsigned short v = ((const unsigned short*)emb)[threadIdx.x & 63];
    int ex = (v >> 7) & 0xFF;
    bool bad = (ex == 0xFF) || (ex > 130) || (ex != 0 && ex < 100);
    return __popcll(__ballot(bad)) > 5;
}

// Pade [5/4] tanh: err < 3e-5 on [-2.2, 2.2], ~1e-6 on [-1,1]
__device__ __forceinline__ float pade_tanh(float x) {
    float u = x * x;
    float num = x * fmaf(u, fmaf(u, 1.0f, 105.0f), 945.0f);
    float den = fmaf(u, fmaf(u, 15.0f, 420.0f), 945.0f);
    return num * __builtin_amdgcn_rcpf(den);
}

template<int CTRL>
__device__ __forceinline__ float dpp_shr(float x) {
    return __int_as_float(__builtin_amdgcn_update_dpp(
        0, __float_as_int(x), CTRL, 0xF, 0xF, true));
}

__device__ __forceinline__ float bperm(int byteidx, float v) {
    return __int_as_float(__builtin_amdgcn_ds_bpermute(byteidx, __float_as_int(v)));
}

__device__ __forceinline__ float rdlane(float v, int l) {
    return __int_as_float(__builtin_amdgcn_readlane(__float_as_int(v), l));
}

// ---------------- Kernel 1: parallel pre-activations ----------------
// pre[t*32 + g*8 + w] = emb_t . W_g[w,:256] + b_g[w] + th_g[w]
template<bool F32>
__device__ __forceinline__ void pre_body(
    const int* __restrict__ sentence, const void* __restrict__ emb,
    const void* Wf, const void* bf_, const void* Wi, const void* bi,
    const void* Wu, const void* bu, const void* Wo, const void* bo,
    const void* thf, const void* thi, const void* thu, const void* tho,
    float* __restrict__ pre, float* se)
{
    const int t = blockIdx.x;
    const int tid = threadIdx.x;
    const int row = sentence[t];
    se[tid] = ldf<F32>(emb, row * EMB + tid);
    __syncthreads();
    const int u = tid >> 3;      // 0..31 output unit (g*8+w)
    const int j = tid & 7;       // 8 threads per unit
    const int g = u >> 3, w = u & 7;
    const void* W  = (g == 0) ? Wf  : (g == 1) ? Wi  : (g == 2) ? Wu  : Wo;
    const void* b  = (g == 0) ? bf_ : (g == 1) ? bi  : (g == 2) ? bu  : bo;
    const void* th = (g == 0) ? thf : (g == 1) ? thi : (g == 2) ? thu : tho;
    float s = 0.f;
    #pragma unroll
    for (int m = 0; m < EMB / 8; ++m) {
        int k = j + m * 8;
        s += se[k] * ldf<F32>(W, w * DIN + k);
    }
    s += __shfl_xor(s, 1, 8);
    s += __shfl_xor(s, 2, 8);
    s += __shfl_xor(s, 4, 8);
    if (j == 0) pre[t * 32 + u] = s + ldf<F32>(b, w) + ldf<F32>(th, w);
}

__global__ __launch_bounds__(256) void k_pre(
    const int* __restrict__ sentence, const void* __restrict__ emb,
    const void* Wf, const void* bf_, const void* Wi, const void* bi,
    const void* Wu, const void* bu, const void* Wo, const void* bo,
    const void* thf, const void* thi, const void* thu, const void* tho,
    float* __restrict__ pre)
{
    __shared__ float se[EMB];
    if (probe_f32(emb))
        pre_body<true >(sentence, emb, Wf, bf_, Wi, bi, Wu, bu, Wo, bo, thf, thi, thu, tho, pre, se);
    else
        pre_body<false>(sentence, emb, Wf, bf_, Wi, bi, Wu, bu, Wo, bo, thf, thi, thu, tho, pre, se);
}

// ---------------- Kernel 2: serial recurrence (one wave) ----------------
// Lanes 0-31: group g = (lane>>3)&3, wire w = lane&7, scan INCLUDES c0:
//   lane w holds S_w = prod_{0..w} c_j = outv_w for w>=1.
// Lanes 32-63: wire w = 7-k (k=lane&7), same prefix scan computes suffix
//   products; upper k==6 holds T7 = prod_{1..7} c_j = outv_0.
// Gather f,i,g,o to wire lanes 0-7 via 4 ds_bpermute; w==0 sources the
// upper-half lane (38/46/54/62).
template<bool F32>
__device__ __forceinline__ void seq_body(
    const void* Wf, const void* Wi, const void* Wu, const void* Wo,
    const float* __restrict__ pre, float* __restrict__ hbuf)
{
    const int lane = threadIdx.x;
    const int k = lane & 7;
    const int g = (lane >> 3) & 3;
    const int w = (lane < 32) ? k : (7 - k);
    const void* W = (g == 0) ? Wf : (g == 1) ? Wi : (g == 2) ? Wu : Wo;
    float Whx[8];
    #pragma unroll
    for (int j = 0; j < 8; ++j) Whx[j] = ldf<F32>(W, w * DIN + EMB + j);
    const int pidx = (g << 3) | w;
    // gather byte-indices (meaningful on lanes 0-7)
    const int bfi = ((k == 0) ? 38 : k) << 2;
    const int bii = ((k == 0) ? 46 : (8 + k)) << 2;
    const int bui = ((k == 0) ? 54 : (16 + k)) << 2;
    const int boi = ((k == 0) ? 62 : (24 + k)) << 2;
    const bool k1 = (k >= 1), k2 = (k >= 2), k4 = (k >= 4);
    // act = ob + os * tanh(as * outv): sigmoid = 0.5 + 0.5*tanh(x/2)
    const float as = (g == 2) ? 1.0f : 0.5f;
    const float os = (g == 2) ? 1.0f : 0.5f;
    const float ob = (g == 2) ? 0.0f : 0.5f;

    float h0 = 0.f, h1 = 0.f, h2 = 0.f, h3 = 0.f;
    float h4 = 0.f, h5 = 0.f, h6 = 0.f, h7 = 0.f;
    float cx = 0.f;
    float pre_next = pre[pidx];

    for (int t = 0; t < SEQ; ++t) {
        float pv = pre_next;
        if (t + 1 < SEQ) pre_next = pre[(t + 1) * 32 + pidx];  // prefetch
        // phi = pv + Whx . h  (two chains for ILP)
        float pa = fmaf(h3, Whx[3], fmaf(h2, Whx[2], fmaf(h1, Whx[1], fmaf(h0, Whx[0], pv))));
        float pb = fmaf(h7, Whx[7], fmaf(h6, Whx[6], fmaf(h5, Whx[5], h4 * Whx[4])));
        float phi = pa + pb;
        float c = __cosf(phi);
        // inclusive product scan over 8-lane groups via DPP (VALU-rate)
        float d = c;
        float t1 = dpp_shr<0x111>(d); d *= (k1 ? t1 : 1.0f);
        float t2 = dpp_shr<0x112>(d); d *= (k2 ? t2 : 1.0f);
        float t4 = dpp_shr<0x114>(d); d *= (k4 ? t4 : 1.0f);
        // activation (polynomial, no exp/div on the chain)
        float act = fmaf(os, pade_tanh(d * as), ob);
        // gather per-wire gate values to lanes 0-7
        float fv = bperm(bfi, act);
        float iv = bperm(bii, act);
        float uv = bperm(bui, act);
        float ov = bperm(boi, act);
        cx = fmaf(fv, cx, iv * uv);
        float hv = ov * pade_tanh(cx);
        if (lane < 8) hbuf[t * 8 + lane] = hv;
        h0 = rdlane(hv, 0); h1 = rdlane(hv, 1);
        h2 = rdlane(hv, 2); h3 = rdlane(hv, 3);
        h4 = rdlane(hv, 4); h5 = rdlane(hv, 5);
        h6 = rdlane(hv, 6); h7 = rdlane(hv, 7);
    }
}

__global__ __launch_bounds__(64) void k_seq(
    const void* __restrict__ emb,
    const void* Wf, const void* Wi, const void* Wu, const void* Wo,
    const float* __restrict__ pre, float* __restrict__ hbuf)
{
    if (probe_f32(emb)) seq_body<true >(Wf, Wi, Wu, Wo, pre, hbuf);
    else                seq_body<false>(Wf, Wi, Wu, Wo, pre, hbuf);
}

// ---------------- Kernel 3: head + log_softmax (one wave / t) ----------------
template<bool F32>
__device__ __forceinline__ void head_body(
    const float* __restrict__ hbuf, const void* Wt, const void* bt,
    void* __restrict__ out)
{
    const int t = blockIdx.x;
    const int l = threadIdx.x;
    float hk[8];
    #pragma unroll
    for (int j = 0; j < 8; ++j) hk[j] = hbuf[t * 8 + j];
    float logit = -INFINITY;
    if (l < TAGS) {
        logit = ldf<F32>(bt, l);
        #pragma unroll
        for (int j = 0; j < 8; ++j) logit += hk[j] * ldf<F32>(Wt, l * 8 + j);
    }
    float m = logit;
    #pragma unroll
    for (int s = 32; s >= 1; s >>= 1) m = fmaxf(m, __shfl_xor(m, s, 64));
    float e = (l < TAGS) ? __expf(logit - m) : 0.f;
    float sum = e;
    #pragma unroll
    for (int s = 32; s >= 1; s >>= 1) sum += __shfl_xor(sum, s, 64);
    if (l < TAGS) {
        float v = logit - m - __logf(sum);
        if constexpr (F32) ((float*)out)[t * TAGS + l] = v;
        else ((unsigned short*)out)[t * TAGS + l] =
                 (unsigned short)(((__float_as_uint(v) + 0x8000u +
                                    ((__float_as_uint(v) >> 16) & 1u)) >> 16));  // RNE bf16
    }
}

__global__ __launch_bounds__(64) void k_head(
    const void* __restrict__ emb,
    const float* __restrict__ hbuf, const void* Wt, const void* bt,
    void* __restrict__ out)
{
    if (probe_f32(emb)) head_body<true >(hbuf, Wt, bt, out);
    else                head_body<false>(hbuf, Wt, bt, out);
}

extern "C" void kernel_launch(void* const* d_in, const int* in_sizes, int n_in,
                              void* d_out, int out_size, void* d_ws, size_t ws_size,
                              hipStream_t stream) {
    (void)in_sizes; (void)n_in; (void)out_size; (void)ws_size;
    const int* sentence = (const int*)d_in[0];
    const void* emb = d_in[1];
    const void* Wf = d_in[2];  const void* bf_ = d_in[3];
    const void* Wi = d_in[4];  const void* bi = d_in[5];
    const void* Wu = d_in[6];  const void* bu = d_in[7];
    const void* Wo = d_in[8];  const void* bo = d_in[9];
    const void* thf = d_in[10]; const void* thi = d_in[11];
    const void* thu = d_in[12]; const void* tho = d_in[13];
    const void* Wt = d_in[14]; const void* bt = d_in[15];

    float* pre  = (float*)d_ws;          // SEQ*32 floats
    float* hbuf = pre + SEQ * 32;        // SEQ*8 floats

    k_pre<<<dim3(SEQ), dim3(256), 0, stream>>>(sentence, emb,
        Wf, bf_, Wi, bi, Wu, bu, Wo, bo, thf, thi, thu, tho, pre);
    k_seq<<<dim3(1), dim3(64), 0, stream>>>(emb, Wf, Wi, Wu, Wo, pre, hbuf);
    k_head<<<dim3(SEQ), dim3(64), 0, stream>>>(emb, hbuf, Wt, bt, d_out);
}

// Round 4
// 731.915 us; speedup vs baseline: 1.3464x; 1.0121x over previous
//
#include <hip/hip_runtime.h>
#include <hip/hip_bf16.h>
#include <math.h>

#define SEQ 2048
#define EMB 256
#define DIN 264   // EMB + HID
#define TAGS 50

// dtype-flexible load: F32 ? float32 : bf16
template<bool F32>
__device__ __forceinline__ float ldf(const void* p, int i) {
    if constexpr (F32) {
        return ((const float*)p)[i];
    } else {
        unsigned int u = ((const unsigned short*)p)[i];
        return __uint_as_float(u << 16);
    }
}

// Per-wave dtype probe on raw 16-bit halves of emb (see R2 notes).
__device__ __forceinline__ bool probe_f32(const void* emb) {
    unsigned short v = ((const unsigned short*)emb)[threadIdx.x & 63];
    int ex = (v >> 7) & 0xFF;
    bool bad = (ex == 0xFF) || (ex > 130) || (ex != 0 && ex < 100);
    return __popcll(__ballot(bad)) > 5;
}

// Pade [5/4] tanh: err < 3e-5 on [-2.2,2.2], < 5e-4 on [-3,3]
__device__ __forceinline__ float pade_tanh(float x) {
    float u = x * x;
    float num = x * fmaf(u, fmaf(u, 1.0f, 105.0f), 945.0f);
    float den = fmaf(u, fmaf(u, 15.0f, 420.0f), 945.0f);
    return num * __builtin_amdgcn_rcpf(den);
}

// row_shr:N with bound_ctrl: invalid source lanes read 0
template<int CTRL>
__device__ __forceinline__ float dpp_shr(float x) {
    return __int_as_float(__builtin_amdgcn_update_dpp(
        0, __float_as_int(x), CTRL, 0xF, 0xF, true));
}

// row_shr:4 with multiplicative-identity masking: wrong-group lanes (bank 2
// of each row: k=0..3 of groups starting at 8,24,40,56) and out-of-row lanes
// (k=0..3 of groups at 0,16,32,48) yield 1.0 instead of garbage/0.
__device__ __forceinline__ float dpp_shr4_id(float x) {
    return __int_as_float(__builtin_amdgcn_update_dpp(
        __float_as_int(1.0f), __float_as_int(x), 0x114, 0xF, 0xB, false));
}

__device__ __forceinline__ float bperm(int byteidx, float v) {
    return __int_as_float(__builtin_amdgcn_ds_bpermute(byteidx, __float_as_int(v)));
}

__device__ __forceinline__ float rdlane(float v, int l) {
    return __int_as_float(__builtin_amdgcn_readlane(__float_as_int(v), l));
}

// ---------------- Kernel 1: parallel pre-activations ----------------
// pre[t*32 + g*8 + w] = emb_t . W_g[w,:256] + b_g[w] + th_g[w]
template<bool F32>
__device__ __forceinline__ void pre_body(
    const int* __restrict__ sentence, const void* __restrict__ emb,
    const void* Wf, const void* bf_, const void* Wi, const void* bi,
    const void* Wu, const void* bu, const void* Wo, const void* bo,
    const void* thf, const void* thi, const void* thu, const void* tho,
    float* __restrict__ pre, float* se)
{
    const int t = blockIdx.x;
    const int tid = threadIdx.x;
    const int row = sentence[t];
    se[tid] = ldf<F32>(emb, row * EMB + tid);
    __syncthreads();
    const int u = tid >> 3;      // 0..31 output unit (g*8+w)
    const int j = tid & 7;       // 8 threads per unit
    const int g = u >> 3, w = u & 7;
    const void* W  = (g == 0) ? Wf  : (g == 1) ? Wi  : (g == 2) ? Wu  : Wo;
    const void* b  = (g == 0) ? bf_ : (g == 1) ? bi  : (g == 2) ? bu  : bo;
    const void* th = (g == 0) ? thf : (g == 1) ? thi : (g == 2) ? thu : tho;
    float s = 0.f;
    #pragma unroll
    for (int m = 0; m < EMB / 8; ++m) {
        int k = j + m * 8;
        s += se[k] * ldf<F32>(W, w * DIN + k);
    }
    s += __shfl_xor(s, 1, 8);
    s += __shfl_xor(s, 2, 8);
    s += __shfl_xor(s, 4, 8);
    if (j == 0) pre[t * 32 + u] = s + ldf<F32>(b, w) + ldf<F32>(th, w);
}

__global__ __launch_bounds__(256) void k_pre(
    const int* __restrict__ sentence, const void* __restrict__ emb,
    const void* Wf, const void* bf_, const void* Wi, const void* bi,
    const void* Wu, const void* bu, const void* Wo, const void* bo,
    const void* thf, const void* thi, const void* thu, const void* tho,
    float* __restrict__ pre)
{
    __shared__ float se[EMB];
    if (probe_f32(emb))
        pre_body<true >(sentence, emb, Wf, bf_, Wi, bi, Wu, bu, Wo, bo, thf, thi, thu, tho, pre, se);
    else
        pre_body<false>(sentence, emb, Wf, bf_, Wi, bi, Wu, bu, Wo, bo, thf, thi, thu, tho, pre, se);
}

// ---------------- Kernel 2: serial recurrence (one wave) ----------------
// Scan-role (gate-major): lanes 0-31: g=(l>>3)&3, w=l&7 — lane holds
//   S_w = prod_{0..w} c_j (= outv_w for w>=1). Lanes 32-63: w=7-k, the same
//   prefix scan computes suffix products; k==6 holds prod_{1..7} = outv_0.
// Cell-role (wire-major, after ONE bpermute transpose): lane l32=l&31:
//   wire wd = (l32>>4)*4 + ((l32&15)>>2), pos = l32&3 with gate order
//   {0:i, 1:u, 2:f, 3:o}. Cell = 3 row-local DPP shr:1 ops.
template<bool F32>
__device__ __forceinline__ void seq_body(
    const void* Wf, const void* Wi, const void* Wu, const void* Wo,
    const float* __restrict__ pre, float* __restrict__ hbuf)
{
    const int lane = threadIdx.x;
    // ---- scan-role ----
    const int k = lane & 7;
    const int g = (lane >> 3) & 3;
    const int w = (lane < 32) ? k : (7 - k);
    const void* W = (g == 0) ? Wf : (g == 1) ? Wi : (g == 2) ? Wu : Wo;
    float Wh[8];
    #pragma unroll
    for (int j = 0; j < 8; ++j) Wh[j] = ldf<F32>(W, w * DIN + EMB + j);
    const int pidx = (g << 3) | w;
    const bool k1 = (k >= 1), k2 = (k >= 2);
    // act = ob + os * tanh(as * outv); sigmoid = 0.5 + 0.5*tanh(x/2); g==2 is tanh
    const float as = (g == 2) ? 1.0f : 0.5f;
    const float os = (g == 2) ? 1.0f : 0.5f;
    const float ob = (g == 2) ? 0.0f : 0.5f;
    // ---- cell-role ----
    const int l32 = lane & 31;
    const int wd = ((l32 >> 4) << 2) | ((l32 & 15) >> 2);
    const int pos = l32 & 3;                       // 0:i 1:u 2:f 3:o
    const int gsel = (pos == 0) ? 1 : (pos == 1) ? 2 : (pos == 2) ? 0 : 3;
    const int bidx = ((wd == 0) ? (32 + 8 * gsel + 6) : (8 * gsel + wd)) << 2;
    const bool do_store = (lane < 32) && (pos == 3);

    float h0 = 0.f, h1 = 0.f, h2 = 0.f, h3 = 0.f;
    float h4 = 0.f, h5 = 0.f, h6 = 0.f, h7 = 0.f;
    float cx = 0.f;
    float pre_next = pre[pidx];

    for (int t = 0; t < SEQ; ++t) {
        float pv = pre_next;
        pre_next = pre[(t + 1) * 32 + pidx];  // t=SEQ-1 reads hbuf area, unused
        // phi = pv + Wh.h  (depth-4 tree)
        float a0 = fmaf(h0, Wh[0], pv);
        float a1 = fmaf(h1, Wh[1], h2 * Wh[2]);
        float a2 = fmaf(h3, Wh[3], h4 * Wh[4]);
        float a3 = fmaf(h5, Wh[5], h6 * Wh[6]);
        float a4 = fmaf(h7, Wh[7], a0);
        float phi = (a1 + a2) + (a3 + a4);
        float c = __cosf(phi);
        // inclusive product scan over 8-lane groups (VALU-rate DPP)
        float d = c;
        float t1 = dpp_shr<0x111>(d); d *= (k1 ? t1 : 1.0f);
        float t2 = dpp_shr<0x112>(d); d *= (k2 ? t2 : 1.0f);
        d *= dpp_shr4_id(d);
        // activation (polynomial)
        float act = fmaf(os, pade_tanh(d * as), ob);
        // ONE transpose to wire-major
        float tr = bperm(bidx, act);
        // LSTM cell via row-local DPP
        float p = tr * dpp_shr<0x111>(tr);           // u-pos: i*u
        cx = fmaf(tr, cx, dpp_shr<0x111>(p));        // f-pos: f*cx + i*u
        float th = pade_tanh(cx);                    // f-pos
        float hv = tr * dpp_shr<0x111>(th);          // o-pos: o*tanh(cx')
        if (do_store) hbuf[t * 8 + wd] = hv;
        h0 = rdlane(hv, 3);  h1 = rdlane(hv, 7);
        h2 = rdlane(hv, 11); h3 = rdlane(hv, 15);
        h4 = rdlane(hv, 19); h5 = rdlane(hv, 23);
        h6 = rdlane(hv, 27); h7 = rdlane(hv, 31);
    }
}

__global__ __launch_bounds__(64) void k_seq(
    const void* __restrict__ emb,
    const void* Wf, const void* Wi, const void* Wu, const void* Wo,
    const float* __restrict__ pre, float* __restrict__ hbuf)
{
    if (probe_f32(emb)) seq_body<true >(Wf, Wi, Wu, Wo, pre, hbuf);
    else                seq_body<false>(Wf, Wi, Wu, Wo, pre, hbuf);
}

// ---------------- Kernel 3: head + log_softmax (one wave / t) ----------------
template<bool F32>
__device__ __forceinline__ void head_body(
    const float* __restrict__ hbuf, const void* Wt, const void* bt,
    void* __restrict__ out)
{
    const int t = blockIdx.x;
    const int l = threadIdx.x;
    float hk[8];
    #pragma unroll
    for (int j = 0; j < 8; ++j) hk[j] = hbuf[t * 8 + j];
    float logit = -INFINITY;
    if (l < TAGS) {
        logit = ldf<F32>(bt, l);
        #pragma unroll
        for (int j = 0; j < 8; ++j) logit += hk[j] * ldf<F32>(Wt, l * 8 + j);
    }
    float m = logit;
    #pragma unroll
    for (int s = 32; s >= 1; s >>= 1) m = fmaxf(m, __shfl_xor(m, s, 64));
    float e = (l < TAGS) ? __expf(logit - m) : 0.f;
    float sum = e;
    #pragma unroll
    for (int s = 32; s >= 1; s >>= 1) sum += __shfl_xor(sum, s, 64);
    if (l < TAGS) {
        float v = logit - m - __logf(sum);
        if constexpr (F32) ((float*)out)[t * TAGS + l] = v;
        else ((unsigned short*)out)[t * TAGS + l] =
                 (unsigned short)(((__float_as_uint(v) + 0x8000u +
                                    ((__float_as_uint(v) >> 16) & 1u)) >> 16));  // RNE bf16
    }
}

__global__ __launch_bounds__(64) void k_head(
    const void* __restrict__ emb,
    const float* __restrict__ hbuf, const void* Wt, const void* bt,
    void* __restrict__ out)
{
    if (probe_f32(emb)) head_body<true >(hbuf, Wt, bt, out);
    else                head_body<false>(hbuf, Wt, bt, out);
}

extern "C" void kernel_launch(void* const* d_in, const int* in_sizes, int n_in,
                              void* d_out, int out_size, void* d_ws, size_t ws_size,
                              hipStream_t stream) {
    (void)in_sizes; (void)n_in; (void)out_size; (void)ws_size;
    const int* sentence = (const int*)d_in[0];
    const void* emb = d_in[1];
    const void* Wf = d_in[2];  const void* bf_ = d_in[3];
    const void* Wi = d_in[4];  const void* bi = d_in[5];
    const void* Wu = d_in[6];  const void* bu = d_in[7];
    const void* Wo = d_in[8];  const void* bo = d_in[9];
    const void* thf = d_in[10]; const void* thi = d_in[11];
    const void* thu = d_in[12]; const void* tho = d_in[13];
    const void* Wt = d_in[14]; const void* bt = d_in[15];

    float* pre  = (float*)d_ws;          // SEQ*32 floats
    float* hbuf = pre + SEQ * 32;        // SEQ*8 floats

    k_pre<<<dim3(SEQ), dim3(256), 0, stream>>>(sentence, emb,
        Wf, bf_, Wi, bi, Wu, bu, Wo, bo, thf, thi, thu, tho, pre);
    k_seq<<<dim3(1), dim3(64), 0, stream>>>(emb, Wf, Wi, Wu, Wo, pre, hbuf);
    k_head<<<dim3(SEQ), dim3(64), 0, stream>>>(emb, hbuf, Wt, bt, d_out);
}

// Round 5
// 662.064 us; speedup vs baseline: 1.4885x; 1.1055x over previous
//
#include <hip/hip_runtime.h>
#include <hip/hip_bf16.h>
#include <math.h>

#define SEQ 2048
#define EMB 256
#define DIN 264   // EMB + HID
#define TAGS 50
#define INV2PI 0.15915494309189535f
#define CHUNK 1024  // LDS ring size (steps)

typedef unsigned v2u __attribute__((ext_vector_type(2)));

#if defined(__has_builtin)
#if __has_builtin(__builtin_amdgcn_permlane32_swap) && __has_builtin(__builtin_amdgcn_permlane16_swap)
#define HAVE_PLSWAP 1
#endif
#endif
#ifndef HAVE_PLSWAP
#define HAVE_PLSWAP 0
#endif

// dtype-flexible load: F32 ? float32 : bf16
template<bool F32>
__device__ __forceinline__ float ldf(const void* p, int i) {
    if constexpr (F32) {
        return ((const float*)p)[i];
    } else {
        unsigned int u = ((const unsigned short*)p)[i];
        return __uint_as_float(u << 16);
    }
}

// Per-wave dtype probe on raw 16-bit halves of emb (see R2 notes).
__device__ __forceinline__ bool probe_f32(const void* emb) {
    unsigned short v = ((const unsigned short*)emb)[threadIdx.x & 63];
    int ex = (v >> 7) & 0xFF;
    bool bad = (ex == 0xFF) || (ex > 130) || (ex != 0 && ex < 100);
    return __popcll(__ballot(bad)) > 5;
}

// Pade [5/4] tanh: err < 3e-5 on [-2.2,2.2] (used for cell, |cx|<=2.1)
__device__ __forceinline__ float pade_tanh(float x) {
    float u = x * x;
    float num = x * fmaf(u, fmaf(u, 1.0f, 105.0f), 945.0f);
    float den = fmaf(u, fmaf(u, 15.0f, 420.0f), 945.0f);
    return num * __builtin_amdgcn_rcpf(den);
}

// Pade [3/2] tanh: err < 3.2e-4 on [-1,1] (used for activation, |arg|<=1)
__device__ __forceinline__ float tanh32(float x) {
    float u = x * x;
    float num = x * (u + 15.0f);
    float den = fmaf(u, 6.0f, 15.0f);
    return num * __builtin_amdgcn_rcpf(den);
}

template<int CTRL>
__device__ __forceinline__ float dpp_shr(float x) {
    return __int_as_float(__builtin_amdgcn_update_dpp(
        0, __float_as_int(x), CTRL, 0xF, 0xF, true));
}
template<int N>
__device__ __forceinline__ float dpp_shl(float x) {
    return __int_as_float(__builtin_amdgcn_update_dpp(
        0, __float_as_int(x), 0x100 | N, 0xF, 0xF, true));
}
// row_shr:4 with multiplicative-identity masking (see R4 notes; bench-proven)
__device__ __forceinline__ float dpp_shr4_id(float x) {
    return __int_as_float(__builtin_amdgcn_update_dpp(
        __float_as_int(1.0f), __float_as_int(x), 0x114, 0xF, 0xB, false));
}
__device__ __forceinline__ float bperm(int byteidx, float v) {
    return __int_as_float(__builtin_amdgcn_ds_bpermute(byteidx, __float_as_int(v)));
}
__device__ __forceinline__ float rdlane(float v, int l) {
    return __int_as_float(__builtin_amdgcn_readlane(__float_as_int(v), l));
}

// ---------------- Kernel 1: parallel pre-activations ----------------
// pre[t*32 + g*8 + w] = (emb_t . W_g[w,:256] + b_g[w] + th_g[w]) / 2pi
template<bool F32>
__device__ __forceinline__ void pre_body(
    const int* __restrict__ sentence, const void* __restrict__ emb,
    const void* Wf, const void* bf_, const void* Wi, const void* bi,
    const void* Wu, const void* bu, const void* Wo, const void* bo,
    const void* thf, const void* thi, const void* thu, const void* tho,
    float* __restrict__ pre, float* se)
{
    const int t = blockIdx.x;
    const int tid = threadIdx.x;
    const int row = sentence[t];
    se[tid] = ldf<F32>(emb, row * EMB + tid);
    __syncthreads();
    const int u = tid >> 3;
    const int j = tid & 7;
    const int g = u >> 3, w = u & 7;
    const void* W  = (g == 0) ? Wf  : (g == 1) ? Wi  : (g == 2) ? Wu  : Wo;
    const void* b  = (g == 0) ? bf_ : (g == 1) ? bi  : (g == 2) ? bu  : bo;
    const void* th = (g == 0) ? thf : (g == 1) ? thi : (g == 2) ? thu : tho;
    float s = 0.f;
    #pragma unroll
    for (int m = 0; m < EMB / 8; ++m) {
        int kk = j + m * 8;
        s += se[kk] * ldf<F32>(W, w * DIN + kk);
    }
    s += __shfl_xor(s, 1, 8);
    s += __shfl_xor(s, 2, 8);
    s += __shfl_xor(s, 4, 8);
    if (j == 0) pre[t * 32 + u] = (s + ldf<F32>(b, w) + ldf<F32>(th, w)) * INV2PI;
}

__global__ __launch_bounds__(256) void k_pre(
    const int* __restrict__ sentence, const void* __restrict__ emb,
    const void* Wf, const void* bf_, const void* Wi, const void* bi,
    const void* Wu, const void* bu, const void* Wo, const void* bo,
    const void* thf, const void* thi, const void* thu, const void* tho,
    float* __restrict__ pre)
{
    __shared__ float se[EMB];
    if (probe_f32(emb))
        pre_body<true >(sentence, emb, Wf, bf_, Wi, bi, Wu, bu, Wo, bo, thf, thi, thu, tho, pre, se);
    else
        pre_body<false>(sentence, emb, Wf, bf_, Wi, bi, Wu, bu, Wo, bo, thf, thi, thu, tho, pre, se);
}

// ---------------- Kernel 2: serial recurrence (one wave) ----------------
// Scan-role (gate-major): lanes 0-31: g=(l>>3)&3, w=l&7; scan includes c0 so
//   lane w holds outv_w for w>=1. Lanes 32-63: w=7-k; same prefix scan gives
//   suffix products; lane 32+8g+6 holds outv_0 for gate g.
// FAST cell: permlane32_swap brings the upper half down (w=0 fix via
//   row_shl:6 + cndmask), permlane16_swap brings u/o rows into f/i rows,
//   row_shl:8 aligns i and o. Cell computed on lanes 0-7. All VALU.
// Fallback cell: 4 ds_bpermute gathers (R3-proven).
template<bool F32, bool FAST>
__device__ __forceinline__ void seq_loop(
    const float* __restrict__ pre, float* __restrict__ hbuf, float* hlds,
    const float (&Wh)[8], int pidx, int k,
    float as, float os, float ob,
    int bfi, int bii, int bui, int boi, bool sel32, bool sel16)
{
    const int lane = threadIdx.x;
    const bool k1 = (k >= 1), k2 = (k >= 2);
    const bool isk0 = (k == 0);
    float h0 = 0.f, h1 = 0.f, h2 = 0.f, h3 = 0.f;
    float h4 = 0.f, h5 = 0.f, h6 = 0.f, h7 = 0.f;
    float cx = 0.f;
    const float* pp = pre + pidx;
    float p0 = pp[0];
    float p1 = pp[32];
    pp += 64;

    for (int t = 0; t < SEQ; ++t) {
        float pv = p0; p0 = p1; p1 = *pp; pp += 32;   // depth-2 prefetch
        // phi/2pi = pv + (Wh/2pi).h
        float a0 = fmaf(h0, Wh[0], pv);
        float a1 = fmaf(h1, Wh[1], h2 * Wh[2]);
        float a2 = fmaf(h3, Wh[3], h4 * Wh[4]);
        float a3 = fmaf(h5, Wh[5], h6 * Wh[6]);
        float phi = (a1 + a2) + (a3 + fmaf(h7, Wh[7], a0));
        float c = __builtin_amdgcn_cosf(phi);         // v_cos: input in revolutions
        // inclusive product scan over 8-lane groups (row-local DPP)
        float d = c;
        float t1 = dpp_shr<0x111>(d); d *= (k1 ? t1 : 1.0f);
        float t2 = dpp_shr<0x112>(d); d *= (k2 ? t2 : 1.0f);
        d *= dpp_shr4_id(d);
        // activation: ob + os*tanh(as*outv)
        float act = fmaf(os, tanh32(d * as), ob);
        float f_, iv, uv, ov;
        if constexpr (FAST) {
            v2u r32 = __builtin_amdgcn_permlane32_swap(
                __float_as_uint(act), __float_as_uint(act), false, false);
            float up = __uint_as_float(sel32 ? r32[1] : r32[0]); // old upper half
            float fix = dpp_shl<6>(up);                // lane 8g <- up[8g+6]
            float act0 = isk0 ? fix : act;
            v2u r16 = __builtin_amdgcn_permlane16_swap(
                __float_as_uint(act0), __float_as_uint(act0), false, false);
            float sw = __uint_as_float(sel16 ? r16[1] : r16[0]); // row1 -> row0
            f_ = act0;               // lanes 0-7: f
            iv = dpp_shl<8>(act0);   // lanes 0-7 <- 8-15: i
            uv = sw;                 // lanes 0-7 <- 16-23: u
            ov = dpp_shl<8>(sw);     // lanes 0-7 <- 24-31: o
        } else {
            f_ = bperm(bfi, act);
            iv = bperm(bii, act);
            uv = bperm(bui, act);
            ov = bperm(boi, act);
        }
        cx = fmaf(f_, cx, iv * uv);
        float th = pade_tanh(cx);
        float hv = ov * th;
        int tm = t & (CHUNK - 1);
        if (lane < 8) hlds[tm * 8 + lane] = hv;
        h0 = rdlane(hv, 0); h1 = rdlane(hv, 1);
        h2 = rdlane(hv, 2); h3 = rdlane(hv, 3);
        h4 = rdlane(hv, 4); h5 = rdlane(hv, 5);
        h6 = rdlane(hv, 6); h7 = rdlane(hv, 7);
        if (tm == CHUNK - 1) {
            // bulk flush LDS chunk -> global (off the per-step chain)
            const float4* ls = (const float4*)hlds;
            float4* gd = (float4*)hbuf + ((t - (CHUNK - 1)) * 8) / 4;
            #pragma unroll 4
            for (int i = lane; i < CHUNK * 8 / 4; i += 64) gd[i] = ls[i];
        }
    }
}

template<bool F32>
__device__ __forceinline__ void seq_body(
    const void* Wf, const void* Wi, const void* Wu, const void* Wo,
    const float* __restrict__ pre, float* __restrict__ hbuf, float* hlds)
{
    const int lane = threadIdx.x;
    const int k = lane & 7;
    const int g = (lane >> 3) & 3;
    const int w = (lane < 32) ? k : (7 - k);
    const void* W = (g == 0) ? Wf : (g == 1) ? Wi : (g == 2) ? Wu : Wo;
    float Wh[8];
    #pragma unroll
    for (int j = 0; j < 8; ++j) Wh[j] = ldf<F32>(W, w * DIN + EMB + j) * INV2PI;
    const int pidx = (g << 3) | w;
    const float as = (g == 2) ? 1.0f : 0.5f;
    const float os = (g == 2) ? 1.0f : 0.5f;
    const float ob = (g == 2) ? 0.0f : 0.5f;
    // bperm fallback gather indices (lanes 0-7 meaningful)
    const int bfi = ((k == 0) ? 38 : k) << 2;
    const int bii = ((k == 0) ? 46 : (8 + k)) << 2;
    const int bui = ((k == 0) ? 54 : (16 + k)) << 2;
    const int boi = ((k == 0) ? 62 : (24 + k)) << 2;

    bool fast = false, sel32 = false, sel16 = false;
#if HAVE_PLSWAP
    {
        // probe the swap builtins' result ordering with lane ids
        unsigned li = (unsigned)lane;
        v2u r = __builtin_amdgcn_permlane32_swap(li, li, false, false);
        bool gx = (lane >= 32) || (r[0] == li + 32);
        bool gy = (lane >= 32) || (r[1] == li + 32);
        bool ax = __popcll(__ballot(gx)) == 64;
        bool ay = __popcll(__ballot(gy)) == 64;
        sel32 = (!ax && ay);
        bool ok32 = ax || ay;
        v2u s = __builtin_amdgcn_permlane16_swap(li, li, false, false);
        bool rowEven = ((lane >> 4) & 1) == 0;
        bool hx = !rowEven || (s[0] == li + 16);
        bool hy = !rowEven || (s[1] == li + 16);
        bool bx = __popcll(__ballot(hx)) == 64;
        bool by = __popcll(__ballot(hy)) == 64;
        sel16 = (!bx && by);
        bool ok16 = bx || by;
        fast = ok32 && ok16;
    }
    if (fast) {
        seq_loop<F32, true>(pre, hbuf, hlds, Wh, pidx, k, as, os, ob,
                            bfi, bii, bui, boi, sel32, sel16);
        return;
    }
#endif
    seq_loop<F32, false>(pre, hbuf, hlds, Wh, pidx, k, as, os, ob,
                         bfi, bii, bui, boi, sel32, sel16);
}

__global__ __launch_bounds__(64) void k_seq(
    const void* __restrict__ emb,
    const void* Wf, const void* Wi, const void* Wu, const void* Wo,
    const float* __restrict__ pre, float* __restrict__ hbuf)
{
    __shared__ float hlds[CHUNK * 8];   // 32 KiB ring
    if (probe_f32(emb)) seq_body<true >(Wf, Wi, Wu, Wo, pre, hbuf, hlds);
    else                seq_body<false>(Wf, Wi, Wu, Wo, pre, hbuf, hlds);
}

// ---------------- Kernel 3: head + log_softmax (one wave / t) ----------------
template<bool F32>
__device__ __forceinline__ void head_body(
    const float* __restrict__ hbuf, const void* Wt, const void* bt,
    void* __restrict__ out)
{
    const int t = blockIdx.x;
    const int l = threadIdx.x;
    float hk[8];
    #pragma unroll
    for (int j = 0; j < 8; ++j) hk[j] = hbuf[t * 8 + j];
    float logit = -INFINITY;
    if (l < TAGS) {
        logit = ldf<F32>(bt, l);
        #pragma unroll
        for (int j = 0; j < 8; ++j) logit += hk[j] * ldf<F32>(Wt, l * 8 + j);
    }
    float m = logit;
    #pragma unroll
    for (int s = 32; s >= 1; s >>= 1) m = fmaxf(m, __shfl_xor(m, s, 64));
    float e = (l < TAGS) ? __expf(logit - m) : 0.f;
    float sum = e;
    #pragma unroll
    for (int s = 32; s >= 1; s >>= 1) sum += __shfl_xor(sum, s, 64);
    if (l < TAGS) {
        float v = logit - m - __logf(sum);
        if constexpr (F32) ((float*)out)[t * TAGS + l] = v;
        else ((unsigned short*)out)[t * TAGS + l] =
                 (unsigned short)(((__float_as_uint(v) + 0x8000u +
                                    ((__float_as_uint(v) >> 16) & 1u)) >> 16));  // RNE bf16
    }
}

__global__ __launch_bounds__(64) void k_head(
    const void* __restrict__ emb,
    const float* __restrict__ hbuf, const void* Wt, const void* bt,
    void* __restrict__ out)
{
    if (probe_f32(emb)) head_body<true >(hbuf, Wt, bt, out);
    else                head_body<false>(hbuf, Wt, bt, out);
}

extern "C" void kernel_launch(void* const* d_in, const int* in_sizes, int n_in,
                              void* d_out, int out_size, void* d_ws, size_t ws_size,
                              hipStream_t stream) {
    (void)in_sizes; (void)n_in; (void)out_size; (void)ws_size;
    const int* sentence = (const int*)d_in[0];
    const void* emb = d_in[1];
    const void* Wf = d_in[2];  const void* bf_ = d_in[3];
    const void* Wi = d_in[4];  const void* bi = d_in[5];
    const void* Wu = d_in[6];  const void* bu = d_in[7];
    const void* Wo = d_in[8];  const void* bo = d_in[9];
    const void* thf = d_in[10]; const void* thi = d_in[11];
    const void* thu = d_in[12]; const void* tho = d_in[13];
    const void* Wt = d_in[14]; const void* bt = d_in[15];

    float* pre  = (float*)d_ws;          // SEQ*32 floats
    float* hbuf = pre + SEQ * 32;        // SEQ*8 floats

    k_pre<<<dim3(SEQ), dim3(256), 0, stream>>>(sentence, emb,
        Wf, bf_, Wi, bi, Wu, bu, Wo, bo, thf, thi, thu, tho, pre);
    k_seq<<<dim3(1), dim3(64), 0, stream>>>(emb, Wf, Wi, Wu, Wo, pre, hbuf);
    k_head<<<dim3(SEQ), dim3(64), 0, stream>>>(emb, hbuf, Wt, bt, d_out);
}

// Round 6
// 524.925 us; speedup vs baseline: 1.8774x; 1.2613x over previous
//
#include <hip/hip_runtime.h>
#include <hip/hip_bf16.h>
#include <math.h>

#define SEQ 2048
#define EMB 256
#define DIN 264   // EMB + HID
#define TAGS 50
#define INV2PI 0.15915494309189535f
#define CHUNK 1024  // LDS ring size (steps)

typedef unsigned v2u __attribute__((ext_vector_type(2)));

#if defined(__has_builtin)
#if __has_builtin(__builtin_amdgcn_permlane32_swap) && __has_builtin(__builtin_amdgcn_permlane16_swap)
#define HAVE_PLSWAP 1
#endif
#endif
#ifndef HAVE_PLSWAP
#define HAVE_PLSWAP 0
#endif

// dtype-flexible load: F32 ? float32 : bf16
template<bool F32>
__device__ __forceinline__ float ldf(const void* p, int i) {
    if constexpr (F32) {
        return ((const float*)p)[i];
    } else {
        unsigned int u = ((const unsigned short*)p)[i];
        return __uint_as_float(u << 16);
    }
}

// Per-wave dtype probe on raw 16-bit halves of emb (see R2 notes).
__device__ __forceinline__ bool probe_f32(const void* emb) {
    unsigned short v = ((const unsigned short*)emb)[threadIdx.x & 63];
    int ex = (v >> 7) & 0xFF;
    bool bad = (ex == 0xFF) || (ex > 130) || (ex != 0 && ex < 100);
    return __popcll(__ballot(bad)) > 5;
}

// Pade [5/4] tanh: err < 3e-5 on [-2.2,2.2] (cell: |cx| <= ~2.1)
__device__ __forceinline__ float pade_tanh(float x) {
    float u = x * x;
    float num = x * fmaf(u, fmaf(u, 1.0f, 105.0f), 945.0f);
    float den = fmaf(u, fmaf(u, 15.0f, 420.0f), 945.0f);
    return num * __builtin_amdgcn_rcpf(den);
}

// Pade [3/2] tanh: err < 3.2e-4 on [-1,1] (activation: |arg| <= 1)
__device__ __forceinline__ float tanh32(float x) {
    float u = x * x;
    float num = x * (u + 15.0f);
    float den = fmaf(u, 6.0f, 15.0f);
    return num * __builtin_amdgcn_rcpf(den);
}

template<int CTRL>
__device__ __forceinline__ float dpp_shr(float x) {
    return __int_as_float(__builtin_amdgcn_update_dpp(
        0, __float_as_int(x), CTRL, 0xF, 0xF, true));
}
template<int N>
__device__ __forceinline__ float dpp_shl(float x) {
    return __int_as_float(__builtin_amdgcn_update_dpp(
        0, __float_as_int(x), 0x100 | N, 0xF, 0xF, true));
}
// row_shr:4 with multiplicative-identity masking (R4-proven)
__device__ __forceinline__ float dpp_shr4_id(float x) {
    return __int_as_float(__builtin_amdgcn_update_dpp(
        __float_as_int(1.0f), __float_as_int(x), 0x114, 0xF, 0xB, false));
}
__device__ __forceinline__ float bperm(int byteidx, float v) {
    return __int_as_float(__builtin_amdgcn_ds_bpermute(byteidx, __float_as_int(v)));
}
__device__ __forceinline__ float rdlane(float v, int l) {
    return __int_as_float(__builtin_amdgcn_readlane(__float_as_int(v), l));
}

// ---------------- Kernel 1: parallel pre-activations ----------------
// pre[t*32 + g*8 + w] = (emb_t . W_g[w,:256] + b_g[w] + th_g[w]) / 2pi
template<bool F32>
__device__ __forceinline__ void pre_body(
    const int* __restrict__ sentence, const void* __restrict__ emb,
    const void* Wf, const void* bf_, const void* Wi, const void* bi,
    const void* Wu, const void* bu, const void* Wo, const void* bo,
    const void* thf, const void* thi, const void* thu, const void* tho,
    float* __restrict__ pre, float* se)
{
    const int t = blockIdx.x;
    const int tid = threadIdx.x;
    const int row = sentence[t];
    se[tid] = ldf<F32>(emb, row * EMB + tid);
    __syncthreads();
    const int u = tid >> 3;
    const int j = tid & 7;
    const int g = u >> 3, w = u & 7;
    const void* W  = (g == 0) ? Wf  : (g == 1) ? Wi  : (g == 2) ? Wu  : Wo;
    const void* b  = (g == 0) ? bf_ : (g == 1) ? bi  : (g == 2) ? bu  : bo;
    const void* th = (g == 0) ? thf : (g == 1) ? thi : (g == 2) ? thu : tho;
    float s = 0.f;
    #pragma unroll
    for (int m = 0; m < EMB / 8; ++m) {
        int kk = j + m * 8;
        s += se[kk] * ldf<F32>(W, w * DIN + kk);
    }
    s += __shfl_xor(s, 1, 8);
    s += __shfl_xor(s, 2, 8);
    s += __shfl_xor(s, 4, 8);
    if (j == 0) pre[t * 32 + u] = (s + ldf<F32>(b, w) + ldf<F32>(th, w)) * INV2PI;
}

__global__ __launch_bounds__(256) void k_pre(
    const int* __restrict__ sentence, const void* __restrict__ emb,
    const void* Wf, const void* bf_, const void* Wi, const void* bi,
    const void* Wu, const void* bu, const void* Wo, const void* bo,
    const void* thf, const void* thi, const void* thu, const void* tho,
    float* __restrict__ pre)
{
    __shared__ float se[EMB];
    if (probe_f32(emb))
        pre_body<true >(sentence, emb, Wf, bf_, Wi, bi, Wu, bu, Wo, bo, thf, thi, thu, tho, pre, se);
    else
        pre_body<false>(sentence, emb, Wf, bf_, Wi, bi, Wu, bu, Wo, bo, thf, thi, thu, tho, pre, se);
}

// ---------------- Kernel 2: serial recurrence (one wave) ----------------
// Scan-role (gate-major): lanes 0-31: g=(l>>3)&3, w=l&7; scan includes c0 so
//   lane w holds outv_w for w>=1. Lanes 32-63: w=7-k; same prefix scan gives
//   suffix products; lane 32+8g+6 holds outv_0 for gate g.
// FAST cell: permlane32_swap + permlane16_swap + row-local DPP (all VALU).
// Fallback cell: 4 ds_bpermute gathers (R3-proven).
// pre is consumed through a distance-8 rotating register pipeline so each
// load is issued ~8 steps before use (covers cross-XCD L3/HBM latency).
template<bool F32, bool FAST>
__device__ __forceinline__ void seq_loop(
    const float* __restrict__ pre, float* __restrict__ hbuf, float* hlds,
    const float (&Wh)[8], int pidx, int k,
    float as, float os, float ob,
    int bfi, int bii, int bui, int boi, bool sel32, bool sel16)
{
    const int lane = threadIdx.x;
    const bool k1 = (k >= 1), k2 = (k >= 2);
    const bool isk0 = (k == 0);
    float h0 = 0.f, h1 = 0.f, h2 = 0.f, h3 = 0.f;
    float h4 = 0.f, h5 = 0.f, h6 = 0.f, h7 = 0.f;
    float cx = 0.f;
    const float* pp = pre + pidx;
    float pb[8];
    #pragma unroll
    for (int i = 0; i < 8; ++i) pb[i] = pp[i * 32];
    pp += 8 * 32;

    for (int tb = 0; tb < SEQ; tb += 8) {
        #pragma unroll
        for (int u = 0; u < 8; ++u) {
            const int t = tb + u;
            float pv = pb[u];
            pb[u] = pp[u * 32];   // prefetch t+8; last block reads hbuf area, unused
            // phi/2pi = pv + (Wh/2pi).h
            float a0 = fmaf(h0, Wh[0], pv);
            float a1 = fmaf(h1, Wh[1], h2 * Wh[2]);
            float a2 = fmaf(h3, Wh[3], h4 * Wh[4]);
            float a3 = fmaf(h5, Wh[5], h6 * Wh[6]);
            float phi = (a1 + a2) + (a3 + fmaf(h7, Wh[7], a0));
            float c = __builtin_amdgcn_cosf(phi);     // input in revolutions
            // inclusive product scan over 8-lane groups (row-local DPP)
            float d = c;
            float t1 = dpp_shr<0x111>(d); d *= (k1 ? t1 : 1.0f);
            float t2 = dpp_shr<0x112>(d); d *= (k2 ? t2 : 1.0f);
            d *= dpp_shr4_id(d);
            // activation: ob + os*tanh(as*outv)
            float act = fmaf(os, tanh32(d * as), ob);
            float f_, iv, uv, ov;
            if constexpr (FAST) {
                v2u r32 = __builtin_amdgcn_permlane32_swap(
                    __float_as_uint(act), __float_as_uint(act), false, false);
                float up = __uint_as_float(sel32 ? r32[1] : r32[0]); // old upper half
                float fix = dpp_shl<6>(up);              // lane 8g <- up[8g+6]
                float act0 = isk0 ? fix : act;
                v2u r16 = __builtin_amdgcn_permlane16_swap(
                    __float_as_uint(act0), __float_as_uint(act0), false, false);
                float sw = __uint_as_float(sel16 ? r16[1] : r16[0]); // row1 -> row0
                f_ = act0;               // lanes 0-7: f
                iv = dpp_shl<8>(act0);   // lanes 0-7 <- 8-15: i
                uv = sw;                 // lanes 0-7 <- 16-23: u
                ov = dpp_shl<8>(sw);     // lanes 0-7 <- 24-31: o
            } else {
                f_ = bperm(bfi, act);
                iv = bperm(bii, act);
                uv = bperm(bui, act);
                ov = bperm(boi, act);
            }
            cx = fmaf(f_, cx, iv * uv);
            float th = pade_tanh(cx);
            float hv = ov * th;
            const int tm = t & (CHUNK - 1);
            if (lane < 8) hlds[tm * 8 + lane] = hv;
            h0 = rdlane(hv, 0); h1 = rdlane(hv, 1);
            h2 = rdlane(hv, 2); h3 = rdlane(hv, 3);
            h4 = rdlane(hv, 4); h5 = rdlane(hv, 5);
            h6 = rdlane(hv, 6); h7 = rdlane(hv, 7);
        }
        pp += 8 * 32;
        if (((tb + 8) & (CHUNK - 1)) == 0) {
            // bulk flush LDS chunk -> global (off the per-step chain)
            const float4* ls = (const float4*)hlds;
            float4* gd = (float4*)hbuf + ((tb + 8 - CHUNK) * 8) / 4;
            #pragma unroll 4
            for (int i = lane; i < CHUNK * 8 / 4; i += 64) gd[i] = ls[i];
        }
    }
}

template<bool F32>
__device__ __forceinline__ void seq_body(
    const void* Wf, const void* Wi, const void* Wu, const void* Wo,
    const float* __restrict__ pre, float* __restrict__ hbuf, float* hlds)
{
    const int lane = threadIdx.x;
    const int k = lane & 7;
    const int g = (lane >> 3) & 3;
    const int w = (lane < 32) ? k : (7 - k);
    const void* W = (g == 0) ? Wf : (g == 1) ? Wi : (g == 2) ? Wu : Wo;
    float Wh[8];
    #pragma unroll
    for (int j = 0; j < 8; ++j) Wh[j] = ldf<F32>(W, w * DIN + EMB + j) * INV2PI;
    const int pidx = (g << 3) | w;
    const float as = (g == 2) ? 1.0f : 0.5f;
    const float os = (g == 2) ? 1.0f : 0.5f;
    const float ob = (g == 2) ? 0.0f : 0.5f;
    // bperm fallback gather indices (lanes 0-7 meaningful)
    const int bfi = ((k == 0) ? 38 : k) << 2;
    const int bii = ((k == 0) ? 46 : (8 + k)) << 2;
    const int bui = ((k == 0) ? 54 : (16 + k)) << 2;
    const int boi = ((k == 0) ? 62 : (24 + k)) << 2;

    bool fast = false, sel32 = false, sel16 = false;
#if HAVE_PLSWAP
    {
        // probe the swap builtins' result ordering with lane ids
        unsigned li = (unsigned)lane;
        v2u r = __builtin_amdgcn_permlane32_swap(li, li, false, false);
        bool gx = (lane >= 32) || (r[0] == li + 32);
        bool gy = (lane >= 32) || (r[1] == li + 32);
        bool ax = __popcll(__ballot(gx)) == 64;
        bool ay = __popcll(__ballot(gy)) == 64;
        sel32 = (!ax && ay);
        bool ok32 = ax || ay;
        v2u s = __builtin_amdgcn_permlane16_swap(li, li, false, false);
        bool rowEven = ((lane >> 4) & 1) == 0;
        bool hx = !rowEven || (s[0] == li + 16);
        bool hy = !rowEven || (s[1] == li + 16);
        bool bx = __popcll(__ballot(hx)) == 64;
        bool by = __popcll(__ballot(hy)) == 64;
        sel16 = (!bx && by);
        bool ok16 = bx || by;
        fast = ok32 && ok16;
    }
    if (fast) {
        seq_loop<F32, true>(pre, hbuf, hlds, Wh, pidx, k, as, os, ob,
                            bfi, bii, bui, boi, sel32, sel16);
        return;
    }
#endif
    seq_loop<F32, false>(pre, hbuf, hlds, Wh, pidx, k, as, os, ob,
                         bfi, bii, bui, boi, sel32, sel16);
}

__global__ __launch_bounds__(64) void k_seq(
    const void* __restrict__ emb,
    const void* Wf, const void* Wi, const void* Wu, const void* Wo,
    const float* __restrict__ pre, float* __restrict__ hbuf)
{
    __shared__ float hlds[CHUNK * 8];   // 32 KiB ring
    if (probe_f32(emb)) seq_body<true >(Wf, Wi, Wu, Wo, pre, hbuf, hlds);
    else                seq_body<false>(Wf, Wi, Wu, Wo, pre, hbuf, hlds);
}

// ---------------- Kernel 3: head + log_softmax (one wave / t) ----------------
template<bool F32>
__device__ __forceinline__ void head_body(
    const float* __restrict__ hbuf, const void* Wt, const void* bt,
    void* __restrict__ out)
{
    const int t = blockIdx.x;
    const int l = threadIdx.x;
    float hk[8];
    #pragma unroll
    for (int j = 0; j < 8; ++j) hk[j] = hbuf[t * 8 + j];
    float logit = -INFINITY;
    if (l < TAGS) {
        logit = ldf<F32>(bt, l);
        #pragma unroll
        for (int j = 0; j < 8; ++j) logit += hk[j] * ldf<F32>(Wt, l * 8 + j);
    }
    float m = logit;
    #pragma unroll
    for (int s = 32; s >= 1; s >>= 1) m = fmaxf(m, __shfl_xor(m, s, 64));
    float e = (l < TAGS) ? __expf(logit - m) : 0.f;
    float sum = e;
    #pragma unroll
    for (int s = 32; s >= 1; s >>= 1) sum += __shfl_xor(sum, s, 64);
    if (l < TAGS) {
        float v = logit - m - __logf(sum);
        if constexpr (F32) ((float*)out)[t * TAGS + l] = v;
        else ((unsigned short*)out)[t * TAGS + l] =
                 (unsigned short)(((__float_as_uint(v) + 0x8000u +
                                    ((__float_as_uint(v) >> 16) & 1u)) >> 16));  // RNE bf16
    }
}

__global__ __launch_bounds__(64) void k_head(
    const void* __restrict__ emb,
    const float* __restrict__ hbuf, const void* Wt, const void* bt,
    void* __restrict__ out)
{
    if (probe_f32(emb)) head_body<true >(hbuf, Wt, bt, out);
    else                head_body<false>(hbuf, Wt, bt, out);
}

extern "C" void kernel_launch(void* const* d_in, const int* in_sizes, int n_in,
                              void* d_out, int out_size, void* d_ws, size_t ws_size,
                              hipStream_t stream) {
    (void)in_sizes; (void)n_in; (void)out_size; (void)ws_size;
    const int* sentence = (const int*)d_in[0];
    const void* emb = d_in[1];
    const void* Wf = d_in[2];  const void* bf_ = d_in[3];
    const void* Wi = d_in[4];  const void* bi = d_in[5];
    const void* Wu = d_in[6];  const void* bu = d_in[7];
    const void* Wo = d_in[8];  const void* bo = d_in[9];
    const void* thf = d_in[10]; const void* thi = d_in[11];
    const void* thu = d_in[12]; const void* tho = d_in[13];
    const void* Wt = d_in[14]; const void* bt = d_in[15];

    float* pre  = (float*)d_ws;          // SEQ*32 floats
    float* hbuf = pre + SEQ * 32;        // SEQ*8 floats

    k_pre<<<dim3(SEQ), dim3(256), 0, stream>>>(sentence, emb,
        Wf, bf_, Wi, bi, Wu, bu, Wo, bo, thf, thi, thu, tho, pre);
    k_seq<<<dim3(1), dim3(64), 0, stream>>>(emb, Wf, Wi, Wu, Wo, pre, hbuf);
    k_head<<<dim3(SEQ), dim3(64), 0, stream>>>(emb, hbuf, Wt, bt, d_out);
}

// Round 7
// 225.114 us; speedup vs baseline: 4.3777x; 2.3318x over previous
//
#include <hip/hip_runtime.h>
#include <hip/hip_bf16.h>
#include <math.h>

#define SEQ 2048
#define EMB 256
#define DIN 264   // EMB + HID
#define TAGS 50
#define INV2PI 0.15915494309189535f
#define CHLEN 64    // output steps per chunk
#define WARM 128    // warmup steps (state contraction <= 0.75/step -> ~1e-12)
#define NCHUNK (SEQ / CHLEN)   // 32 blocks

typedef unsigned v2u __attribute__((ext_vector_type(2)));

#if defined(__has_builtin)
#if __has_builtin(__builtin_amdgcn_permlane32_swap) && __has_builtin(__builtin_amdgcn_permlane16_swap)
#define HAVE_PLSWAP 1
#endif
#endif
#ifndef HAVE_PLSWAP
#define HAVE_PLSWAP 0
#endif

// dtype-flexible load: F32 ? float32 : bf16
template<bool F32>
__device__ __forceinline__ float ldf(const void* p, int i) {
    if constexpr (F32) {
        return ((const float*)p)[i];
    } else {
        unsigned int u = ((const unsigned short*)p)[i];
        return __uint_as_float(u << 16);
    }
}

// Per-wave dtype probe on raw 16-bit halves of emb (see R2 notes).
__device__ __forceinline__ bool probe_f32(const void* emb) {
    unsigned short v = ((const unsigned short*)emb)[threadIdx.x & 63];
    int ex = (v >> 7) & 0xFF;
    bool bad = (ex == 0xFF) || (ex > 130) || (ex != 0 && ex < 100);
    return __popcll(__ballot(bad)) > 5;
}

// Pade [5/4] tanh: err < 3e-5 on [-2.2,2.2] (cell: |cx| <= ~2.1)
__device__ __forceinline__ float pade_tanh(float x) {
    float u = x * x;
    float num = x * fmaf(u, fmaf(u, 1.0f, 105.0f), 945.0f);
    float den = fmaf(u, fmaf(u, 15.0f, 420.0f), 945.0f);
    return num * __builtin_amdgcn_rcpf(den);
}

// Pade [3/2] tanh: err < 3.2e-4 on [-1,1] (activation: |arg| <= 1)
__device__ __forceinline__ float tanh32(float x) {
    float u = x * x;
    float num = x * (u + 15.0f);
    float den = fmaf(u, 6.0f, 15.0f);
    return num * __builtin_amdgcn_rcpf(den);
}

template<int CTRL>
__device__ __forceinline__ float dpp_shr(float x) {
    return __int_as_float(__builtin_amdgcn_update_dpp(
        0, __float_as_int(x), CTRL, 0xF, 0xF, true));
}
template<int N>
__device__ __forceinline__ float dpp_shl(float x) {
    return __int_as_float(__builtin_amdgcn_update_dpp(
        0, __float_as_int(x), 0x100 | N, 0xF, 0xF, true));
}
// row_shr:4 with multiplicative-identity masking (R4-proven)
__device__ __forceinline__ float dpp_shr4_id(float x) {
    return __int_as_float(__builtin_amdgcn_update_dpp(
        __float_as_int(1.0f), __float_as_int(x), 0x114, 0xF, 0xB, false));
}
__device__ __forceinline__ float bperm(int byteidx, float v) {
    return __int_as_float(__builtin_amdgcn_ds_bpermute(byteidx, __float_as_int(v)));
}
__device__ __forceinline__ float rdlane(float v, int l) {
    return __int_as_float(__builtin_amdgcn_readlane(__float_as_int(v), l));
}

// ---------------- Kernel 1: parallel pre-activations ----------------
// pre[t*32 + g*8 + w] = (emb_t . W_g[w,:256] + b_g[w] + th_g[w]) / 2pi
template<bool F32>
__device__ __forceinline__ void pre_body(
    const int* __restrict__ sentence, const void* __restrict__ emb,
    const void* Wf, const void* bf_, const void* Wi, const void* bi,
    const void* Wu, const void* bu, const void* Wo, const void* bo,
    const void* thf, const void* thi, const void* thu, const void* tho,
    float* __restrict__ pre, float* se)
{
    const int t = blockIdx.x;
    const int tid = threadIdx.x;
    const int row = sentence[t];
    se[tid] = ldf<F32>(emb, row * EMB + tid);
    __syncthreads();
    const int u = tid >> 3;
    const int j = tid & 7;
    const int g = u >> 3, w = u & 7;
    const void* W  = (g == 0) ? Wf  : (g == 1) ? Wi  : (g == 2) ? Wu  : Wo;
    const void* b  = (g == 0) ? bf_ : (g == 1) ? bi  : (g == 2) ? bu  : bo;
    const void* th = (g == 0) ? thf : (g == 1) ? thi : (g == 2) ? thu : tho;
    float s = 0.f;
    #pragma unroll
    for (int m = 0; m < EMB / 8; ++m) {
        int kk = j + m * 8;
        s += se[kk] * ldf<F32>(W, w * DIN + kk);
    }
    s += __shfl_xor(s, 1, 8);
    s += __shfl_xor(s, 2, 8);
    s += __shfl_xor(s, 4, 8);
    if (j == 0) pre[t * 32 + u] = (s + ldf<F32>(b, w) + ldf<F32>(th, w)) * INV2PI;
}

__global__ __launch_bounds__(256) void k_pre(
    const int* __restrict__ sentence, const void* __restrict__ emb,
    const void* Wf, const void* bf_, const void* Wi, const void* bi,
    const void* Wu, const void* bu, const void* Wo, const void* bo,
    const void* thf, const void* thi, const void* thu, const void* tho,
    float* __restrict__ pre)
{
    __shared__ float se[EMB];
    if (probe_f32(emb))
        pre_body<true >(sentence, emb, Wf, bf_, Wi, bi, Wu, bu, Wo, bo, thf, thi, thu, tho, pre, se);
    else
        pre_body<false>(sentence, emb, Wf, bf_, Wi, bi, Wu, bu, Wo, bo, thf, thi, thu, tho, pre, se);
}

// ---------------- Kernel 2: chunk-parallel recurrence ----------------
// NCHUNK blocks x 1 wave. Block b computes outputs [64b, 64b+64) after a
// WARM-step warmup from zero state (forget gate <= sigma(1)=0.731 =>
// init-state error < 1e-12 by output time). Per-step body identical to the
// R6-proven kernel (scan incl. c0 on lower half, suffix half for outv0,
// permlane-swap cell with bperm fallback, distance-8 pre prefetch).
template<bool F32, bool FAST>
__device__ __forceinline__ void seq_loop(
    const float* __restrict__ pre, float* __restrict__ hbuf, float* hlds,
    const float (&Wh)[8], int pidx, int k,
    float as, float os, float ob,
    int bfi, int bii, int bui, int boi, bool sel32, bool sel16,
    int start, int endt, int t_out)
{
    const int lane = threadIdx.x;
    const bool k1 = (k >= 1), k2 = (k >= 2);
    const bool isk0 = (k == 0);
    float h0 = 0.f, h1 = 0.f, h2 = 0.f, h3 = 0.f;
    float h4 = 0.f, h5 = 0.f, h6 = 0.f, h7 = 0.f;
    float cx = 0.f;
    const float* pp = pre + start * 32 + pidx;
    float pb[8];
    #pragma unroll
    for (int i = 0; i < 8; ++i) pb[i] = pp[i * 32];
    pp += 8 * 32;

    for (int tb = start; tb < endt; tb += 8) {
        #pragma unroll
        for (int u = 0; u < 8; ++u) {
            const int t = tb + u;
            float pv = pb[u];
            pb[u] = pp[u * 32];   // prefetch t+8; tail reads hbuf area, unused
            // phi/2pi = pv + (Wh/2pi).h
            float a0 = fmaf(h0, Wh[0], pv);
            float a1 = fmaf(h1, Wh[1], h2 * Wh[2]);
            float a2 = fmaf(h3, Wh[3], h4 * Wh[4]);
            float a3 = fmaf(h5, Wh[5], h6 * Wh[6]);
            float phi = (a1 + a2) + (a3 + fmaf(h7, Wh[7], a0));
            float c = __builtin_amdgcn_cosf(phi);     // input in revolutions
            // inclusive product scan over 8-lane groups (row-local DPP)
            float d = c;
            float t1 = dpp_shr<0x111>(d); d *= (k1 ? t1 : 1.0f);
            float t2 = dpp_shr<0x112>(d); d *= (k2 ? t2 : 1.0f);
            d *= dpp_shr4_id(d);
            // activation: ob + os*tanh(as*outv)
            float act = fmaf(os, tanh32(d * as), ob);
            float f_, iv, uv, ov;
            if constexpr (FAST) {
                v2u r32 = __builtin_amdgcn_permlane32_swap(
                    __float_as_uint(act), __float_as_uint(act), false, false);
                float up = __uint_as_float(sel32 ? r32[1] : r32[0]); // old upper half
                float fix = dpp_shl<6>(up);              // lane 8g <- up[8g+6]
                float act0 = isk0 ? fix : act;
                v2u r16 = __builtin_amdgcn_permlane16_swap(
                    __float_as_uint(act0), __float_as_uint(act0), false, false);
                float sw = __uint_as_float(sel16 ? r16[1] : r16[0]); // row1 -> row0
                f_ = act0;               // lanes 0-7: f
                iv = dpp_shl<8>(act0);   // lanes 0-7 <- 8-15: i
                uv = sw;                 // lanes 0-7 <- 16-23: u
                ov = dpp_shl<8>(sw);     // lanes 0-7 <- 24-31: o
            } else {
                f_ = bperm(bfi, act);
                iv = bperm(bii, act);
                uv = bperm(bui, act);
                ov = bperm(boi, act);
            }
            cx = fmaf(f_, cx, iv * uv);
            float th = pade_tanh(cx);
            float hv = ov * th;
            int idx = t - t_out;                  // warm steps clamp to slot 0
            idx = idx < 0 ? 0 : idx;
            if (lane < 8) hlds[idx * 8 + lane] = hv;
            h0 = rdlane(hv, 0); h1 = rdlane(hv, 1);
            h2 = rdlane(hv, 2); h3 = rdlane(hv, 3);
            h4 = rdlane(hv, 4); h5 = rdlane(hv, 5);
            h6 = rdlane(hv, 6); h7 = rdlane(hv, 7);
        }
        pp += 8 * 32;
    }
    // flush chunk outputs: CHLEN*8 floats = 128 float4
    __builtin_amdgcn_s_waitcnt(0);  // ensure LDS stores visible (same wave; cheap)
    const float4* ls = (const float4*)hlds;
    float4* gd = (float4*)(hbuf + t_out * 8);
    #pragma unroll
    for (int i = lane; i < CHLEN * 8 / 4; i += 64) gd[i] = ls[i];
}

template<bool F32>
__device__ __forceinline__ void seq_body(
    const void* Wf, const void* Wi, const void* Wu, const void* Wo,
    const float* __restrict__ pre, float* __restrict__ hbuf, float* hlds)
{
    const int lane = threadIdx.x;
    const int k = lane & 7;
    const int g = (lane >> 3) & 3;
    const int w = (lane < 32) ? k : (7 - k);
    const void* W = (g == 0) ? Wf : (g == 1) ? Wi : (g == 2) ? Wu : Wo;
    float Wh[8];
    #pragma unroll
    for (int j = 0; j < 8; ++j) Wh[j] = ldf<F32>(W, w * DIN + EMB + j) * INV2PI;
    const int pidx = (g << 3) | w;
    const float as = (g == 2) ? 1.0f : 0.5f;
    const float os = (g == 2) ? 1.0f : 0.5f;
    const float ob = (g == 2) ? 0.0f : 0.5f;
    // bperm fallback gather indices (lanes 0-7 meaningful)
    const int bfi = ((k == 0) ? 38 : k) << 2;
    const int bii = ((k == 0) ? 46 : (8 + k)) << 2;
    const int bui = ((k == 0) ? 54 : (16 + k)) << 2;
    const int boi = ((k == 0) ? 62 : (24 + k)) << 2;
    // chunk range
    const int t_out = blockIdx.x * CHLEN;
    const int start = (t_out >= WARM) ? (t_out - WARM) : 0;
    const int endt = t_out + CHLEN;

    bool fast = false, sel32 = false, sel16 = false;
#if HAVE_PLSWAP
    {
        // probe the swap builtins' result ordering with lane ids
        unsigned li = (unsigned)lane;
        v2u r = __builtin_amdgcn_permlane32_swap(li, li, false, false);
        bool gx = (lane >= 32) || (r[0] == li + 32);
        bool gy = (lane >= 32) || (r[1] == li + 32);
        bool ax = __popcll(__ballot(gx)) == 64;
        bool ay = __popcll(__ballot(gy)) == 64;
        sel32 = (!ax && ay);
        bool ok32 = ax || ay;
        v2u s = __builtin_amdgcn_permlane16_swap(li, li, false, false);
        bool rowEven = ((lane >> 4) & 1) == 0;
        bool hx = !rowEven || (s[0] == li + 16);
        bool hy = !rowEven || (s[1] == li + 16);
        bool bx = __popcll(__ballot(hx)) == 64;
        bool by = __popcll(__ballot(hy)) == 64;
        sel16 = (!bx && by);
        bool ok16 = bx || by;
        fast = ok32 && ok16;
    }
    if (fast) {
        seq_loop<F32, true>(pre, hbuf, hlds, Wh, pidx, k, as, os, ob,
                            bfi, bii, bui, boi, sel32, sel16,
                            start, endt, t_out);
        return;
    }
#endif
    seq_loop<F32, false>(pre, hbuf, hlds, Wh, pidx, k, as, os, ob,
                         bfi, bii, bui, boi, sel32, sel16,
                         start, endt, t_out);
}

__global__ __launch_bounds__(64) void k_seq(
    const void* __restrict__ emb,
    const void* Wf, const void* Wi, const void* Wu, const void* Wo,
    const float* __restrict__ pre, float* __restrict__ hbuf)
{
    __shared__ float hlds[CHLEN * 8];   // 2 KiB ring (output steps only)
    if (probe_f32(emb)) seq_body<true >(Wf, Wi, Wu, Wo, pre, hbuf, hlds);
    else                seq_body<false>(Wf, Wi, Wu, Wo, pre, hbuf, hlds);
}

// ---------------- Kernel 3: head + log_softmax (one wave / t) ----------------
template<bool F32>
__device__ __forceinline__ void head_body(
    const float* __restrict__ hbuf, const void* Wt, const void* bt,
    void* __restrict__ out)
{
    const int t = blockIdx.x;
    const int l = threadIdx.x;
    float hk[8];
    #pragma unroll
    for (int j = 0; j < 8; ++j) hk[j] = hbuf[t * 8 + j];
    float logit = -INFINITY;
    if (l < TAGS) {
        logit = ldf<F32>(bt, l);
        #pragma unroll
        for (int j = 0; j < 8; ++j) logit += hk[j] * ldf<F32>(Wt, l * 8 + j);
    }
    float m = logit;
    #pragma unroll
    for (int s = 32; s >= 1; s >>= 1) m = fmaxf(m, __shfl_xor(m, s, 64));
    float e = (l < TAGS) ? __expf(logit - m) : 0.f;
    float sum = e;
    #pragma unroll
    for (int s = 32; s >= 1; s >>= 1) sum += __shfl_xor(sum, s, 64);
    if (l < TAGS) {
        float v = logit - m - __logf(sum);
        if constexpr (F32) ((float*)out)[t * TAGS + l] = v;
        else ((unsigned short*)out)[t * TAGS + l] =
                 (unsigned short)(((__float_as_uint(v) + 0x8000u +
                                    ((__float_as_uint(v) >> 16) & 1u)) >> 16));  // RNE bf16
    }
}

__global__ __launch_bounds__(64) void k_head(
    const void* __restrict__ emb,
    const float* __restrict__ hbuf, const void* Wt, const void* bt,
    void* __restrict__ out)
{
    if (probe_f32(emb)) head_body<true >(hbuf, Wt, bt, out);
    else                head_body<false>(hbuf, Wt, bt, out);
}

extern "C" void kernel_launch(void* const* d_in, const int* in_sizes, int n_in,
                              void* d_out, int out_size, void* d_ws, size_t ws_size,
                              hipStream_t stream) {
    (void)in_sizes; (void)n_in; (void)out_size; (void)ws_size;
    const int* sentence = (const int*)d_in[0];
    const void* emb = d_in[1];
    const void* Wf = d_in[2];  const void* bf_ = d_in[3];
    const void* Wi = d_in[4];  const void* bi = d_in[5];
    const void* Wu = d_in[6];  const void* bu = d_in[7];
    const void* Wo = d_in[8];  const void* bo = d_in[9];
    const void* thf = d_in[10]; const void* thi = d_in[11];
    const void* thu = d_in[12]; const void* tho = d_in[13];
    const void* Wt = d_in[14]; const void* bt = d_in[15];

    float* pre  = (float*)d_ws;          // SEQ*32 floats
    float* hbuf = pre + SEQ * 32;        // SEQ*8 floats

    k_pre<<<dim3(SEQ), dim3(256), 0, stream>>>(sentence, emb,
        Wf, bf_, Wi, bi, Wu, bu, Wo, bo, thf, thi, thu, tho, pre);
    k_seq<<<dim3(NCHUNK), dim3(64), 0, stream>>>(emb, Wf, Wi, Wu, Wo, pre, hbuf);
    k_head<<<dim3(SEQ), dim3(64), 0, stream>>>(emb, hbuf, Wt, bt, d_out);
}

// Round 8
// 210.270 us; speedup vs baseline: 4.6867x; 1.0706x over previous
//
#include <hip/hip_runtime.h>
#include <hip/hip_bf16.h>
#include <math.h>

#define SEQ 2048
#define EMB 256
#define DIN 264   // EMB + HID
#define TAGS 50
#define INV2PI 0.15915494309189535f
#define CHLEN 32    // output steps per chunk
#define WARM 64     // warmup steps (contraction <= ~0.79/step -> ~3e-7 residual)
#define NCHUNK (SEQ / CHLEN)   // 64 blocks

typedef unsigned v2u __attribute__((ext_vector_type(2)));

#if defined(__has_builtin)
#if __has_builtin(__builtin_amdgcn_permlane32_swap) && __has_builtin(__builtin_amdgcn_permlane16_swap)
#define HAVE_PLSWAP 1
#endif
#endif
#ifndef HAVE_PLSWAP
#define HAVE_PLSWAP 0
#endif

// dtype-flexible load: F32 ? float32 : bf16
template<bool F32>
__device__ __forceinline__ float ldf(const void* p, int i) {
    if constexpr (F32) {
        return ((const float*)p)[i];
    } else {
        unsigned int u = ((const unsigned short*)p)[i];
        return __uint_as_float(u << 16);
    }
}

// 8 consecutive elements via 16B vector loads (both paths 16B-aligned for
// our offsets: DIN*elt_size multiples of 16 at row starts, offs multiple of 8)
template<bool F32>
__device__ __forceinline__ void ld8(const void* p, int elem_off, float* out) {
    if constexpr (F32) {
        const float4* q = (const float4*)((const float*)p + elem_off);
        float4 a = q[0], b = q[1];
        out[0]=a.x; out[1]=a.y; out[2]=a.z; out[3]=a.w;
        out[4]=b.x; out[5]=b.y; out[6]=b.z; out[7]=b.w;
    } else {
        const uint4* q = (const uint4*)((const unsigned short*)p + elem_off);
        uint4 a = q[0];
        out[0]=__uint_as_float(a.x << 16); out[1]=__uint_as_float(a.x & 0xFFFF0000u);
        out[2]=__uint_as_float(a.y << 16); out[3]=__uint_as_float(a.y & 0xFFFF0000u);
        out[4]=__uint_as_float(a.z << 16); out[5]=__uint_as_float(a.z & 0xFFFF0000u);
        out[6]=__uint_as_float(a.w << 16); out[7]=__uint_as_float(a.w & 0xFFFF0000u);
    }
}

// Per-wave dtype probe on raw 16-bit halves of emb (see R2 notes).
__device__ __forceinline__ bool probe_f32(const void* emb) {
    unsigned short v = ((const unsigned short*)emb)[threadIdx.x & 63];
    int ex = (v >> 7) & 0xFF;
    bool bad = (ex == 0xFF) || (ex > 130) || (ex != 0 && ex < 100);
    return __popcll(__ballot(bad)) > 5;
}

// Pade [5/4] tanh: err < 3e-5 on [-2.2,2.2] (cell: |cx| <= ~2.1)
__device__ __forceinline__ float pade_tanh(float x) {
    float u = x * x;
    float num = x * fmaf(u, fmaf(u, 1.0f, 105.0f), 945.0f);
    float den = fmaf(u, fmaf(u, 15.0f, 420.0f), 945.0f);
    return num * __builtin_amdgcn_rcpf(den);
}

// Pade [3/2] tanh: err < 3.2e-4 on [-1,1] (activation: |arg| <= 1)
__device__ __forceinline__ float tanh32(float x) {
    float u = x * x;
    float num = x * (u + 15.0f);
    float den = fmaf(u, 6.0f, 15.0f);
    return num * __builtin_amdgcn_rcpf(den);
}

template<int CTRL>
__device__ __forceinline__ float dpp_shr(float x) {
    return __int_as_float(__builtin_amdgcn_update_dpp(
        0, __float_as_int(x), CTRL, 0xF, 0xF, true));
}
template<int N>
__device__ __forceinline__ float dpp_shl(float x) {
    return __int_as_float(__builtin_amdgcn_update_dpp(
        0, __float_as_int(x), 0x100 | N, 0xF, 0xF, true));
}
// row_shr:4 with multiplicative-identity masking (R4-proven)
__device__ __forceinline__ float dpp_shr4_id(float x) {
    return __int_as_float(__builtin_amdgcn_update_dpp(
        __float_as_int(1.0f), __float_as_int(x), 0x114, 0xF, 0xB, false));
}
__device__ __forceinline__ float bperm(int byteidx, float v) {
    return __int_as_float(__builtin_amdgcn_ds_bpermute(byteidx, __float_as_int(v)));
}
__device__ __forceinline__ float rdlane(float v, int l) {
    return __int_as_float(__builtin_amdgcn_readlane(__float_as_int(v), l));
}

// ---------------- Kernel 1: parallel pre-activations ----------------
// pre[t*32 + g*8 + w] = (emb_t . W_g[w,:256] + b_g[w] + th_g[w]) / 2pi
// Thread j of each unit covers spans {j*8 + m*64 .. +8}, m=0..3:
//   global W loads are 16B-vector; LDS banks (8j+i) mod 32 are at most
//   2-way aliased across the wave (free on CDNA4, m136).
template<bool F32>
__device__ __forceinline__ void pre_body(
    const int* __restrict__ sentence, const void* __restrict__ emb,
    const void* Wf, const void* bf_, const void* Wi, const void* bi,
    const void* Wu, const void* bu, const void* Wo, const void* bo,
    const void* thf, const void* thi, const void* thu, const void* tho,
    float* __restrict__ pre, float* se)
{
    const int t = blockIdx.x;
    const int tid = threadIdx.x;
    const int row = sentence[t];
    se[tid] = ldf<F32>(emb, row * EMB + tid);
    __syncthreads();
    const int u = tid >> 3;
    const int j = tid & 7;
    const int g = u >> 3, w = u & 7;
    const void* W  = (g == 0) ? Wf  : (g == 1) ? Wi  : (g == 2) ? Wu  : Wo;
    const void* b  = (g == 0) ? bf_ : (g == 1) ? bi  : (g == 2) ? bu  : bo;
    const void* th = (g == 0) ? thf : (g == 1) ? thi : (g == 2) ? thu : tho;
    float s = 0.f;
    #pragma unroll
    for (int m = 0; m < 4; ++m) {
        const int off = j * 8 + m * 64;
        float wv[8];
        ld8<F32>(W, w * DIN + off, wv);
        #pragma unroll
        for (int i = 0; i < 8; ++i) s += se[off + i] * wv[i];
    }
    s += __shfl_xor(s, 1, 8);
    s += __shfl_xor(s, 2, 8);
    s += __shfl_xor(s, 4, 8);
    if (j == 0) pre[t * 32 + u] = (s + ldf<F32>(b, w) + ldf<F32>(th, w)) * INV2PI;
}

__global__ __launch_bounds__(256) void k_pre(
    const int* __restrict__ sentence, const void* __restrict__ emb,
    const void* Wf, const void* bf_, const void* Wi, const void* bi,
    const void* Wu, const void* bu, const void* Wo, const void* bo,
    const void* thf, const void* thi, const void* thu, const void* tho,
    float* __restrict__ pre)
{
    __shared__ float se[EMB];
    if (probe_f32(emb))
        pre_body<true >(sentence, emb, Wf, bf_, Wi, bi, Wu, bu, Wo, bo, thf, thi, thu, tho, pre, se);
    else
        pre_body<false>(sentence, emb, Wf, bf_, Wi, bi, Wu, bu, Wo, bo, thf, thi, thu, tho, pre, se);
}

// ---------------- Kernel 2: chunk-parallel recurrence ----------------
// NCHUNK blocks x 1 wave. Block b computes outputs [CHLEN*b, CHLEN*(b+1))
// after a WARM-step warmup from zero state (forget gate <= sigma(1)=0.731
// + small h-coupling => contraction ~0.79/step; 0.79^64 ~ 3e-7).
// Per-step body identical to the R6-proven kernel.
template<bool F32, bool FAST>
__device__ __forceinline__ void seq_loop(
    const float* __restrict__ pre, float* __restrict__ hbuf, float* hlds,
    const float (&Wh)[8], int pidx, int k,
    float as, float os, float ob,
    int bfi, int bii, int bui, int boi, bool sel32, bool sel16,
    int start, int endt, int t_out)
{
    const int lane = threadIdx.x;
    const bool k1 = (k >= 1), k2 = (k >= 2);
    const bool isk0 = (k == 0);
    float h0 = 0.f, h1 = 0.f, h2 = 0.f, h3 = 0.f;
    float h4 = 0.f, h5 = 0.f, h6 = 0.f, h7 = 0.f;
    float cx = 0.f;
    const float* pp = pre + start * 32 + pidx;
    float pb[8];
    #pragma unroll
    for (int i = 0; i < 8; ++i) pb[i] = pp[i * 32];
    pp += 8 * 32;

    for (int tb = start; tb < endt; tb += 8) {
        #pragma unroll
        for (int u = 0; u < 8; ++u) {
            const int t = tb + u;
            float pv = pb[u];
            pb[u] = pp[u * 32];   // prefetch t+8; tail reads past-chunk, unused
            // phi/2pi = pv + (Wh/2pi).h
            float a0 = fmaf(h0, Wh[0], pv);
            float a1 = fmaf(h1, Wh[1], h2 * Wh[2]);
            float a2 = fmaf(h3, Wh[3], h4 * Wh[4]);
            float a3 = fmaf(h5, Wh[5], h6 * Wh[6]);
            float phi = (a1 + a2) + (a3 + fmaf(h7, Wh[7], a0));
            float c = __builtin_amdgcn_cosf(phi);     // input in revolutions
            // inclusive product scan over 8-lane groups (row-local DPP)
            float d = c;
            float t1 = dpp_shr<0x111>(d); d *= (k1 ? t1 : 1.0f);
            float t2 = dpp_shr<0x112>(d); d *= (k2 ? t2 : 1.0f);
            d *= dpp_shr4_id(d);
            // activation: ob + os*tanh(as*outv)
            float act = fmaf(os, tanh32(d * as), ob);
            float f_, iv, uv, ov;
            if constexpr (FAST) {
                v2u r32 = __builtin_amdgcn_permlane32_swap(
                    __float_as_uint(act), __float_as_uint(act), false, false);
                float up = __uint_as_float(sel32 ? r32[1] : r32[0]); // old upper half
                float fix = dpp_shl<6>(up);              // lane 8g <- up[8g+6]
                float act0 = isk0 ? fix : act;
                v2u r16 = __builtin_amdgcn_permlane16_swap(
                    __float_as_uint(act0), __float_as_uint(act0), false, false);
                float sw = __uint_as_float(sel16 ? r16[1] : r16[0]); // row1 -> row0
                f_ = act0;               // lanes 0-7: f
                iv = dpp_shl<8>(act0);   // lanes 0-7 <- 8-15: i
                uv = sw;                 // lanes 0-7 <- 16-23: u
                ov = dpp_shl<8>(sw);     // lanes 0-7 <- 24-31: o
            } else {
                f_ = bperm(bfi, act);
                iv = bperm(bii, act);
                uv = bperm(bui, act);
                ov = bperm(boi, act);
            }
            cx = fmaf(f_, cx, iv * uv);
            float th = pade_tanh(cx);
            float hv = ov * th;
            int idx = t - t_out;                  // warm steps clamp to slot 0
            idx = idx < 0 ? 0 : idx;
            if (lane < 8) hlds[idx * 8 + lane] = hv;
            h0 = rdlane(hv, 0); h1 = rdlane(hv, 1);
            h2 = rdlane(hv, 2); h3 = rdlane(hv, 3);
            h4 = rdlane(hv, 4); h5 = rdlane(hv, 5);
            h6 = rdlane(hv, 6); h7 = rdlane(hv, 7);
        }
        pp += 8 * 32;
    }
    // flush chunk outputs: CHLEN*8 floats
    __builtin_amdgcn_s_waitcnt(0);  // ensure LDS stores visible (same wave)
    const float4* ls = (const float4*)hlds;
    float4* gd = (float4*)(hbuf + t_out * 8);
    #pragma unroll
    for (int i = lane; i < CHLEN * 8 / 4; i += 64) gd[i] = ls[i];
}

template<bool F32>
__device__ __forceinline__ void seq_body(
    const void* Wf, const void* Wi, const void* Wu, const void* Wo,
    const float* __restrict__ pre, float* __restrict__ hbuf, float* hlds)
{
    const int lane = threadIdx.x;
    const int k = lane & 7;
    const int g = (lane >> 3) & 3;
    const int w = (lane < 32) ? k : (7 - k);
    const void* W = (g == 0) ? Wf : (g == 1) ? Wi : (g == 2) ? Wu : Wo;
    float Wh[8];
    #pragma unroll
    for (int j = 0; j < 8; ++j) Wh[j] = ldf<F32>(W, w * DIN + EMB + j) * INV2PI;
    const int pidx = (g << 3) | w;
    const float as = (g == 2) ? 1.0f : 0.5f;
    const float os = (g == 2) ? 1.0f : 0.5f;
    const float ob = (g == 2) ? 0.0f : 0.5f;
    // bperm fallback gather indices (lanes 0-7 meaningful)
    const int bfi = ((k == 0) ? 38 : k) << 2;
    const int bii = ((k == 0) ? 46 : (8 + k)) << 2;
    const int bui = ((k == 0) ? 54 : (16 + k)) << 2;
    const int boi = ((k == 0) ? 62 : (24 + k)) << 2;
    // chunk range
    const int t_out = blockIdx.x * CHLEN;
    const int start = (t_out >= WARM) ? (t_out - WARM) : 0;
    const int endt = t_out + CHLEN;

    bool fast = false, sel32 = false, sel16 = false;
#if HAVE_PLSWAP
    {
        // probe the swap builtins' result ordering with lane ids
        unsigned li = (unsigned)lane;
        v2u r = __builtin_amdgcn_permlane32_swap(li, li, false, false);
        bool gx = (lane >= 32) || (r[0] == li + 32);
        bool gy = (lane >= 32) || (r[1] == li + 32);
        bool ax = __popcll(__ballot(gx)) == 64;
        bool ay = __popcll(__ballot(gy)) == 64;
        sel32 = (!ax && ay);
        bool ok32 = ax || ay;
        v2u s = __builtin_amdgcn_permlane16_swap(li, li, false, false);
        bool rowEven = ((lane >> 4) & 1) == 0;
        bool hx = !rowEven || (s[0] == li + 16);
        bool hy = !rowEven || (s[1] == li + 16);
        bool bx = __popcll(__ballot(hx)) == 64;
        bool by = __popcll(__ballot(hy)) == 64;
        sel16 = (!bx && by);
        bool ok16 = bx || by;
        fast = ok32 && ok16;
    }
    if (fast) {
        seq_loop<F32, true>(pre, hbuf, hlds, Wh, pidx, k, as, os, ob,
                            bfi, bii, bui, boi, sel32, sel16,
                            start, endt, t_out);
        return;
    }
#endif
    seq_loop<F32, false>(pre, hbuf, hlds, Wh, pidx, k, as, os, ob,
                         bfi, bii, bui, boi, sel32, sel16,
                         start, endt, t_out);
}

__global__ __launch_bounds__(64) void k_seq(
    const void* __restrict__ emb,
    const void* Wf, const void* Wi, const void* Wu, const void* Wo,
    const float* __restrict__ pre, float* __restrict__ hbuf)
{
    __shared__ float hlds[CHLEN * 8];   // 1 KiB (output steps only)
    if (probe_f32(emb)) seq_body<true >(Wf, Wi, Wu, Wo, pre, hbuf, hlds);
    else                seq_body<false>(Wf, Wi, Wu, Wo, pre, hbuf, hlds);
}

// ---------------- Kernel 3: head + log_softmax (one wave / t) ----------------
template<bool F32>
__device__ __forceinline__ void head_body(
    const float* __restrict__ hbuf, const void* Wt, const void* bt,
    void* __restrict__ out)
{
    const int t = blockIdx.x;
    const int l = threadIdx.x;
    float hk[8];
    #pragma unroll
    for (int j = 0; j < 8; ++j) hk[j] = hbuf[t * 8 + j];
    float logit = -INFINITY;
    if (l < TAGS) {
        logit = ldf<F32>(bt, l);
        #pragma unroll
        for (int j = 0; j < 8; ++j) logit += hk[j] * ldf<F32>(Wt, l * 8 + j);
    }
    float m = logit;
    #pragma unroll
    for (int s = 32; s >= 1; s >>= 1) m = fmaxf(m, __shfl_xor(m, s, 64));
    float e = (l < TAGS) ? __expf(logit - m) : 0.f;
    float sum = e;
    #pragma unroll
    for (int s = 32; s >= 1; s >>= 1) sum += __shfl_xor(sum, s, 64);
    if (l < TAGS) {
        float v = logit - m - __logf(sum);
        if constexpr (F32) ((float*)out)[t * TAGS + l] = v;
        else ((unsigned short*)out)[t * TAGS + l] =
                 (unsigned short)(((__float_as_uint(v) + 0x8000u +
                                    ((__float_as_uint(v) >> 16) & 1u)) >> 16));  // RNE bf16
    }
}

__global__ __launch_bounds__(64) void k_head(
    const void* __restrict__ emb,
    const float* __restrict__ hbuf, const void* Wt, const void* bt,
    void* __restrict__ out)
{
    if (probe_f32(emb)) head_body<true >(hbuf, Wt, bt, out);
    else                head_body<false>(hbuf, Wt, bt, out);
}

extern "C" void kernel_launch(void* const* d_in, const int* in_sizes, int n_in,
                              void* d_out, int out_size, void* d_ws, size_t ws_size,
                              hipStream_t stream) {
    (void)in_sizes; (void)n_in; (void)out_size; (void)ws_size;
    const int* sentence = (const int*)d_in[0];
    const void* emb = d_in[1];
    const void* Wf = d_in[2];  const void* bf_ = d_in[3];
    const void* Wi = d_in[4];  const void* bi = d_in[5];
    const void* Wu = d_in[6];  const void* bu = d_in[7];
    const void* Wo = d_in[8];  const void* bo = d_in[9];
    const void* thf = d_in[10]; const void* thi = d_in[11];
    const void* thu = d_in[12]; const void* tho = d_in[13];
    const void* Wt = d_in[14]; const void* bt = d_in[15];

    float* pre  = (float*)d_ws;          // SEQ*32 floats
    float* hbuf = pre + SEQ * 32;        // SEQ*8 floats

    k_pre<<<dim3(SEQ), dim3(256), 0, stream>>>(sentence, emb,
        Wf, bf_, Wi, bi, Wu, bu, Wo, bo, thf, thi, thu, tho, pre);
    k_seq<<<dim3(NCHUNK), dim3(64), 0, stream>>>(emb, Wf, Wi, Wu, Wo, pre, hbuf);
    k_head<<<dim3(SEQ), dim3(64), 0, stream>>>(emb, hbuf, Wt, bt, d_out);
}